// Round 12
// baseline (349.818 us; speedup 1.0000x reference)
//
#include <hip/hip_runtime.h>

#define NN 100000
#define NE 800000
#define DD 16
#define CAP 28
#define ALPHA 0.1f

typedef _Float16 h2_t __attribute__((ext_vector_type(2)));
union U32H2 { unsigned u; h2_t h; };

__device__ __forceinline__ unsigned pack2h(float a, float b) {
  U32H2 v; v.h[0] = (_Float16)a; v.h[1] = (_Float16)b; return v.u;
}

// f32 += f16x2 . f16x2  (mixed-precision dot2); exact-math fallback if absent
__device__ __forceinline__ float dot2(unsigned a, unsigned b, float c) {
  U32H2 ua, ub; ua.u = a; ub.u = b;
#if __has_builtin(__builtin_amdgcn_fdot2)
  return __builtin_amdgcn_fdot2(ua.h, ub.h, c, false);
#else
  return fmaf((float)ua.h[0], (float)ub.h[0],
         fmaf((float)ua.h[1], (float)ub.h[1], c));
#endif
}

__device__ __forceinline__ void load16(const float* __restrict__ p, float* r) {
  float4 v0 = *(const float4*)(p + 0);
  float4 v1 = *(const float4*)(p + 4);
  float4 v2 = *(const float4*)(p + 8);
  float4 v3 = *(const float4*)(p + 12);
  r[0]=v0.x; r[1]=v0.y; r[2]=v0.z; r[3]=v0.w;
  r[4]=v1.x; r[5]=v1.y; r[6]=v1.z; r[7]=v1.w;
  r[8]=v2.x; r[9]=v2.y; r[10]=v2.z; r[11]=v2.w;
  r[12]=v3.x; r[13]=v3.y; r[14]=v3.z; r[15]=v3.w;
}

__device__ __forceinline__ void store16(float* __restrict__ p, const float* r) {
  *(float4*)(p + 0)  = make_float4(r[0], r[1], r[2], r[3]);
  *(float4*)(p + 4)  = make_float4(r[4], r[5], r[6], r[7]);
  *(float4*)(p + 8)  = make_float4(r[8], r[9], r[10], r[11]);
  *(float4*)(p + 12) = make_float4(r[12], r[13], r[14], r[15]);
}

// ---------------------------------------------------------------------------
// Fused build: one pass. pos = atomicAdd(cnt[key]); slot write at key*CAP+pos.
// pay entry: {w0 = nbr:17 | e2f15:15, w1 = f16x2(e0,e1)}; nbr==0x1FFFF => self-loop
// au entry (src side): {dst, a}
// ---------------------------------------------------------------------------
__global__ __launch_bounds__(256) void build_kernel(
    const int* __restrict__ ei, const float* __restrict__ ea, const float* __restrict__ a,
    int* __restrict__ cnt, uint2* __restrict__ pay, uint2* __restrict__ au)
{
  int e = blockIdx.x * 256 + threadIdx.x;
  if (e >= NE) return;
  int s = ei[e];
  int d = ei[NE + e];
  float e0 = ea[3 * (size_t)e], e1 = ea[3 * (size_t)e + 1], e2 = ea[3 * (size_t)e + 2];
  unsigned e01 = pack2h(e0, e1);
  U32H2 t; t.h[0] = (_Float16)e2; t.h[1] = (_Float16)0.0f;
  unsigned e2b = (t.u & 0xFFFFu) >> 1;          // 15-bit f16 (mantissa LSB dropped)
  int sl = (s == d);
  unsigned nb_d = sl ? 0x1FFFFu : (unsigned)s;
  unsigned nb_s = sl ? 0x1FFFFu : (unsigned)d;

  int pd = atomicAdd(&cnt[d], 1);
  if (pd < CAP) pay[(size_t)d * CAP + pd] = make_uint2(nb_d | (e2b << 17), e01);
  int ps = atomicAdd(&cnt[NN + s], 1);
  if (ps < CAP) {
    pay[(size_t)(NN + s) * CAP + ps] = make_uint2(nb_s | (e2b << 17), e01);
    au[(size_t)s * CAP + ps] = make_uint2((unsigned)d, __float_as_uint(a[e]));
  }
}

// ---------------------------------------------------------------------------
// Degree-bucket permutation of the 2N (node,dir) groups (64 buckets).
// ---------------------------------------------------------------------------
__global__ __launch_bounds__(256) void dbucket_kernel(
    const int* __restrict__ cnt, int* __restrict__ dhist)
{
  __shared__ int lh[64];
  int t = threadIdx.x;
  if (t < 64) lh[t] = 0;
  __syncthreads();
  int g = blockIdx.x * 256 + t;
  if (g < 2 * NN) {
    int dg = min(cnt[g], CAP);
    atomicAdd(&lh[min(dg, 63)], 1);
  }
  __syncthreads();
  if (t < 64 && lh[t]) atomicAdd(&dhist[t], lh[t]);
}

__global__ void dscan64_kernel(int* __restrict__ dhist)
{
  int t = threadIdx.x;   // 64 threads
  int v = dhist[t];
  int x = v;
  #pragma unroll
  for (int off = 1; off < 64; off <<= 1) {
    int y = __shfl_up(x, off, 64);
    if (t >= off) x += y;
  }
  dhist[t] = x - v;      // exclusive base; becomes cursor for dperm
}

__global__ __launch_bounds__(256) void dperm_kernel(
    const int* __restrict__ cnt, int* __restrict__ dhist, int* __restrict__ perm)
{
  __shared__ int lh[64];
  __shared__ int lb[64];
  int t = threadIdx.x;
  if (t < 64) lh[t] = 0;
  __syncthreads();
  int g = blockIdx.x * 256 + t;
  int b = 0, r = 0;
  bool v = (g < 2 * NN);
  if (v) {
    int dg = min(cnt[g], CAP);
    b = min(dg, 63);
    r = atomicAdd(&lh[b], 1);
  }
  __syncthreads();
  if (t < 64 && lh[t]) lb[t] = atomicAdd(&dhist[t], lh[t]);
  __syncthreads();
  if (v) perm[lb[b] + r] = g;
}

// ---------------------------------------------------------------------------
// Gather: 8-lane subgroup per degree-sorted (node,dir) group; slot-table CSR.
// Neighbor + attr(e0,e1) matmul via f16 dot2 (weights pre-paired in LDS).
// ---------------------------------------------------------------------------
template<bool FIRST, bool WITH_AU>
__global__ __launch_bounds__(256) void gather_kernel(
    const float* __restrict__ h, const unsigned* __restrict__ hb,
    const uint2* __restrict__ pay, const int* __restrict__ cnt,
    const int* __restrict__ perm,
    const float* __restrict__ to_w1, const float* __restrict__ to_b1,
    const float* __restrict__ to_w2, const float* __restrict__ to_b2,
    const float* __restrict__ fr_w1, const float* __restrict__ fr_b1,
    const float* __restrict__ fr_w2, const float* __restrict__ fr_b2,
    float* __restrict__ mto, float* __restrict__ mfr, int gblocks,
    const uint2* __restrict__ au, const float* __restrict__ u,
    const float* __restrict__ y, float w, float* __restrict__ loss)
{
  if (WITH_AU && (int)blockIdx.x >= gblocks) {
    // ---- au_loss body ----
    __shared__ float ss[4];
    int n = (blockIdx.x - gblocks) * 256 + threadIdx.x;
    float acc = 0.0f;
    if (n < NN) {
      float auv = 0.0f;
      int deg = min(cnt[NN + n], CAP);
      const uint2* ap = au + (size_t)n * CAP;
      for (int i = 0; i < deg; ++i) {
        uint2 q = ap[i];
        auv = fmaf(__uint_as_float(q.y), u[(int)q.x], auv);
      }
      float dlt = auv - y[n];
      acc = dlt * dlt;
    }
    #pragma unroll
    for (int off = 32; off > 0; off >>= 1) acc += __shfl_down(acc, off);
    int lane = threadIdx.x & 63, wid = threadIdx.x >> 6;
    if (lane == 0) ss[wid] = acc;
    __syncthreads();
    if (threadIdx.x == 0) atomicAdd(loss, (ss[0] + ss[1] + ss[2] + ss[3]) * w);
    return;
  }

  // ---- gather body ----
  __shared__ float sw[1696];       // per half (848): w1[560] b1@560 w2@576 b2@832
  __shared__ unsigned w1h[2][144]; // f16 pairs: kp<8 rows {16+2kp,17+2kp}; kp=8 rows {32,33}
  __shared__ float p1buf[512];
  int t = threadIdx.x;
  for (int i = t; i < 560; i += 256) { sw[i] = to_w1[i]; sw[848 + i] = fr_w1[i]; }
  { int i = t;
    if (i < 256) { sw[576 + i] = to_w2[i]; sw[848 + 576 + i] = fr_w2[i]; }
    if (i < 16) {
      sw[560 + i] = to_b1[i];
      sw[832 + i] = to_b2[i];
      sw[848 + 560 + i] = fr_b1[i];
      sw[848 + 832 + i] = fr_b2[i];
    }
  }
  for (int i = t; i < 288; i += 256) {
    int dr = i / 144, idx = i % 144;
    int kp = idx >> 4, j = idx & 15;
    int r0 = (kp < 8) ? (16 + 2 * kp) : 32;
    const float* W = dr ? fr_w1 : to_w1;
    w1h[dr][idx] = pack2h(W[r0 * DD + j], W[(r0 + 1) * DD + j]);
  }
  __syncthreads();

  int sub = (blockIdx.x * 256 + t) >> 3;   // subgroup index (exact: 2N*8 threads)
  int l = t & 7;
  int g = perm[sub];                       // degree-sorted group
  int dir = (g >= NN) ? 1 : 0;             // 0 = mess_to, 1 = mess_from
  int n = g - (dir ? NN : 0);

  const float* w1 = sw + (dir ? 848 : 0);
  const float* b1 = w1 + 560;
  const float* w2 = w1 + 576;
  const float* b2 = w1 + 832;
  const unsigned* whn = w1h[dir];          // neighbor pairs [kp*16+j]
  const unsigned* wha = w1h[dir] + 128;    // attr rows 32,33 pairs [j]

  float p1v[DD];
  if (FIRST) {
    #pragma unroll
    for (int j = 0; j < DD; ++j) p1v[j] = b1[j];
  } else {
    // cooperative p1: lane l computes outputs 2l,2l+1 (32 FMA), exchange via LDS
    float hv[DD];
    load16(h + (size_t)n * DD, hv);
    int j0 = 2 * l;
    float pa = b1[j0], pb = b1[j0 + 1];
    #pragma unroll
    for (int k = 0; k < DD; ++k) {
      pa = fmaf(hv[k], w1[k * DD + j0], pa);
      pb = fmaf(hv[k], w1[k * DD + j0 + 1], pb);
    }
    p1buf[2 * t] = pa;
    p1buf[2 * t + 1] = pb;
    __syncthreads();
    const float* pbase = &p1buf[(t & ~7) * 2];
    #pragma unroll
    for (int j = 0; j < DD; ++j) p1v[j] = pbase[j];
  }

  float hs_[DD];
  #pragma unroll
  for (int j = 0; j < DD; ++j) hs_[j] = 0.0f;
  int cntv = 0;

  int deg = min(cnt[g], CAP);
  const uint2* pp = pay + (size_t)g * CAP;
  for (int i = l; i < deg; i += 8) {
    uint2 q = pp[i];
    unsigned nb = q.x & 0x1FFFFu;
    if (nb != 0x1FFFFu) {
      unsigned e01 = q.y;
      U32H2 te; te.u = ((q.x >> 17) << 1) & 0xFFFFu;
      float e2f = (float)te.h[0];
      float hid[DD];
      #pragma unroll
      for (int j = 0; j < DD; ++j)
        hid[j] = fmaf(e2f, w1[34 * DD + j], dot2(e01, wha[j], p1v[j]));
      if (!FIRST) {
        uint4 qa = *(const uint4*)(hb + (size_t)nb * 8);
        uint4 qb = *(const uint4*)(hb + (size_t)nb * 8 + 4);
        unsigned hp[8] = {qa.x, qa.y, qa.z, qa.w, qb.x, qb.y, qb.z, qb.w};
        #pragma unroll
        for (int kp = 0; kp < 8; ++kp) {
          unsigned hv2 = hp[kp];
          #pragma unroll
          for (int j = 0; j < DD; ++j) hid[j] = dot2(hv2, whn[kp * 16 + j], hid[j]);
        }
      }
      #pragma unroll
      for (int j = 0; j < DD; ++j) hs_[j] += fmaxf(hid[j], 0.0f);
      ++cntv;
    }
  }

  // reduce across the 8-lane subgroup
  #pragma unroll
  for (int j = 0; j < DD; ++j) {
    hs_[j] += __shfl_xor(hs_[j], 1, 64);
    hs_[j] += __shfl_xor(hs_[j], 2, 64);
    hs_[j] += __shfl_xor(hs_[j], 4, 64);
  }
  cntv += __shfl_xor(cntv, 1, 64);
  cntv += __shfl_xor(cntv, 2, 64);
  cntv += __shfl_xor(cntv, 4, 64);

  // layer 2 once per group, feature-split: lane l emits outputs [2l, 2l+2)
  float c = (float)cntv;
  float m0 = c * b2[2 * l + 0];
  float m1 = c * b2[2 * l + 1];
  #pragma unroll
  for (int k = 0; k < DD; ++k) {
    float x = hs_[k];
    m0 = fmaf(x, w2[k * DD + 2 * l + 0], m0);
    m1 = fmaf(x, w2[k * DD + 2 * l + 1], m1);
  }
  float* dst = (dir ? mfr : mto) + (size_t)n * DD + 2 * l;
  *(float2*)dst = make_float2(m0, m1);
}

// ---------------------------------------------------------------------------
// Node kernel: h += ALPHA*psi([h,mto,mfr,prb]); u = dec(h); hb = f16(h)
// FIRST=true: h == 0 -> skip h load and its 16 rows.
// ---------------------------------------------------------------------------
template<bool FIRST>
__global__ __launch_bounds__(256) void node_kernel(
    float* __restrict__ h, unsigned* __restrict__ hb,
    const float* __restrict__ mto, const float* __restrict__ mfr,
    const float* __restrict__ prb,
    const float* __restrict__ psi_w1, const float* __restrict__ psi_b1,
    const float* __restrict__ psi_w2, const float* __restrict__ psi_b2,
    const float* __restrict__ dec_w1, const float* __restrict__ dec_b1,
    const float* __restrict__ dec_w2, const float* __restrict__ dec_b2,
    float* __restrict__ u)
{
  __shared__ float sw[1361];
  for (int i = threadIdx.x; i < 784; i += 256) sw[i] = psi_w1[i];
  { int i = threadIdx.x;
    if (i < 256) { sw[800 + i] = psi_w2[i]; sw[1072 + i] = dec_w1[i]; }
    if (i < 16) {
      sw[784 + i] = psi_b1[i];
      sw[1056 + i] = psi_b2[i];
      sw[1328 + i] = dec_b1[i];
      sw[1344 + i] = dec_w2[i];
    }
    if (i == 0) sw[1360] = dec_b2[0];
  }
  __syncthreads();

  int n = blockIdx.x * 256 + threadIdx.x;
  if (n >= NN) return;

  float hv[DD], mt[DD], mf[DD];
  if (!FIRST) {
    load16(h + (size_t)n * DD, hv);
  } else {
    for (int j = 0; j < DD; ++j) hv[j] = 0.0f;
  }
  load16(mto + (size_t)n * DD, mt);
  load16(mfr + (size_t)n * DD, mf);
  float p = prb[n];

  float hid[DD];
  #pragma unroll
  for (int j = 0; j < DD; ++j) hid[j] = sw[784 + j];
  if (!FIRST) {
    #pragma unroll
    for (int i = 0; i < DD; ++i) {
      float x = hv[i];
      #pragma unroll
      for (int j = 0; j < DD; ++j) hid[j] = fmaf(x, sw[i * DD + j], hid[j]);
    }
  }
  #pragma unroll
  for (int i = 0; i < DD; ++i) {
    float x = mt[i];
    #pragma unroll
    for (int j = 0; j < DD; ++j) hid[j] = fmaf(x, sw[(DD + i) * DD + j], hid[j]);
  }
  #pragma unroll
  for (int i = 0; i < DD; ++i) {
    float x = mf[i];
    #pragma unroll
    for (int j = 0; j < DD; ++j) hid[j] = fmaf(x, sw[(2 * DD + i) * DD + j], hid[j]);
  }
  #pragma unroll
  for (int j = 0; j < DD; ++j) hid[j] = fmaf(p, sw[48 * DD + j], hid[j]);
  #pragma unroll
  for (int j = 0; j < DD; ++j) hid[j] = fmaxf(hid[j], 0.0f);

  float hnew[DD];
  #pragma unroll
  for (int j = 0; j < DD; ++j) hnew[j] = sw[1056 + j];
  #pragma unroll
  for (int i = 0; i < DD; ++i) {
    float x = hid[i];
    #pragma unroll
    for (int j = 0; j < DD; ++j) hnew[j] = fmaf(x, sw[800 + i * DD + j], hnew[j]);
  }
  #pragma unroll
  for (int j = 0; j < DD; ++j) hnew[j] = fmaf(ALPHA, hnew[j], hv[j]);
  store16(h + (size_t)n * DD, hnew);

  uint4 pa, pb;
  pa.x = pack2h(hnew[0],  hnew[1]);
  pa.y = pack2h(hnew[2],  hnew[3]);
  pa.z = pack2h(hnew[4],  hnew[5]);
  pa.w = pack2h(hnew[6],  hnew[7]);
  pb.x = pack2h(hnew[8],  hnew[9]);
  pb.y = pack2h(hnew[10], hnew[11]);
  pb.z = pack2h(hnew[12], hnew[13]);
  pb.w = pack2h(hnew[14], hnew[15]);
  *(uint4*)(hb + (size_t)n * 8)     = pa;
  *(uint4*)(hb + (size_t)n * 8 + 4) = pb;

  float hid2[DD];
  #pragma unroll
  for (int j = 0; j < DD; ++j) hid2[j] = sw[1328 + j];
  #pragma unroll
  for (int i = 0; i < DD; ++i) {
    float x = hnew[i];
    #pragma unroll
    for (int j = 0; j < DD; ++j) hid2[j] = fmaf(x, sw[1072 + i * DD + j], hid2[j]);
  }
  float uo = sw[1360];
  #pragma unroll
  for (int i = 0; i < DD; ++i) uo += fmaxf(hid2[i], 0.0f) * sw[1344 + i];
  u[n] = uo;
}

extern "C" void kernel_launch(void* const* d_in, const int* in_sizes, int n_in,
                              void* d_out, int out_size, void* d_ws, size_t ws_size,
                              hipStream_t stream) {
  const int*   ei        = (const int*)d_in[0];
  const float* ea        = (const float*)d_in[1];
  const float* a_ij      = (const float*)d_in[2];
  const float* prb       = (const float*)d_in[3];
  const float* y         = (const float*)d_in[5];
  const float* phi_to_w1 = (const float*)d_in[6];
  const float* phi_to_b1 = (const float*)d_in[7];
  const float* phi_to_w2 = (const float*)d_in[8];
  const float* phi_to_b2 = (const float*)d_in[9];
  const float* phi_fr_w1 = (const float*)d_in[10];
  const float* phi_fr_b1 = (const float*)d_in[11];
  const float* phi_fr_w2 = (const float*)d_in[12];
  const float* phi_fr_b2 = (const float*)d_in[13];
  const float* psi_w1    = (const float*)d_in[14];
  const float* psi_b1    = (const float*)d_in[15];
  const float* psi_w2    = (const float*)d_in[16];
  const float* psi_b2    = (const float*)d_in[17];
  const float* dec_w1    = (const float*)d_in[18];
  const float* dec_b1    = (const float*)d_in[19];
  const float* dec_w2    = (const float*)d_in[20];
  const float* dec_b2    = (const float*)d_in[21];

  float* out_u    = (float*)d_out;
  float* out_loss = out_u + NN;

  char* wp = (char*)d_ws;
  auto carve = [&](size_t bytes) { void* p = (void*)wp; wp += (bytes + 15) & ~(size_t)15; return p; };
  uint2*    pay   = (uint2*)carve((size_t)2 * NN * CAP * 8);  // slot table [2N][CAP]
  uint2*    au    = (uint2*)carve((size_t)NN * CAP * 8);      // au slots [N][CAP]
  float*    h     = (float*)carve((size_t)NN * DD * 4);
  unsigned* hb16  = (unsigned*)carve((size_t)NN * 8 * 4);     // f16x2 pairs, 8 u32/node
  float*    mto   = (float*)carve((size_t)NN * DD * 4);
  float*    mfr   = (float*)carve((size_t)NN * DD * 4);
  int*      cnt   = (int*)carve((size_t)2 * NN * 4);
  int*      dhist = (int*)carve(64 * 4);                      // contiguous after cnt
  int*      perm  = (int*)carve((size_t)2 * NN * 4);

  hipMemsetAsync(out_loss, 0, 4, stream);
  hipMemsetAsync(cnt, 0, ((size_t)2 * NN + 64) * 4, stream);  // cnt + dhist

  const int EB  = (NE + 255) / 256;             // 3125
  const int NB  = (NN + 255) / 256;             // 391
  const int L2N = 2 * NN;                       // 200000
  const int DB  = (L2N + 255) / 256;            // 782
  const int GB8 = (L2N * 8) / 256;              // 6250 (exact)

  build_kernel<<<EB, 256, 0, stream>>>(ei, ea, a_ij, cnt, pay, au);
  dbucket_kernel<<<DB, 256, 0, stream>>>(cnt, dhist);
  dscan64_kernel<<<1, 64, 0, stream>>>(dhist);
  dperm_kernel<<<DB, 256, 0, stream>>>(cnt, dhist, perm);

  const float gw[3] = {0.81f, 0.9f, 1.0f};  // gamma^(K-1-t)

  // t = 0 (h == 0)
  gather_kernel<true, false><<<GB8, 256, 0, stream>>>(
      h, hb16, pay, cnt, perm,
      phi_to_w1, phi_to_b1, phi_to_w2, phi_to_b2,
      phi_fr_w1, phi_fr_b1, phi_fr_w2, phi_fr_b2,
      mto, mfr, GB8, au, out_u, y, 0.0f, out_loss);
  node_kernel<true><<<NB, 256, 0, stream>>>(
      h, hb16, mto, mfr, prb,
      psi_w1, psi_b1, psi_w2, psi_b2,
      dec_w1, dec_b1, dec_w2, dec_b2, out_u);

  // t = 1, 2: gather(t) fused with au_loss(t-1)
  for (int t = 1; t < 3; ++t) {
    gather_kernel<false, true><<<GB8 + NB, 256, 0, stream>>>(
        h, hb16, pay, cnt, perm,
        phi_to_w1 + t * 560, phi_to_b1 + t * 16, phi_to_w2 + t * 256, phi_to_b2 + t * 16,
        phi_fr_w1 + t * 560, phi_fr_b1 + t * 16, phi_fr_w2 + t * 256, phi_fr_b2 + t * 16,
        mto, mfr, GB8, au, out_u, y, gw[t - 1] / (float)NN, out_loss);
    node_kernel<false><<<NB, 256, 0, stream>>>(
        h, hb16, mto, mfr, prb,
        psi_w1 + t * 784, psi_b1 + t * 16, psi_w2 + t * 256, psi_b2 + t * 16,
        dec_w1 + t * 256, dec_b1 + t * 16, dec_w2 + t * 16, dec_b2 + t, out_u);
  }

  // final residual loss (t = 2's u)
  gather_kernel<false, true><<<NB, 256, 0, stream>>>(
      h, hb16, pay, cnt, perm,
      phi_to_w1, phi_to_b1, phi_to_w2, phi_to_b2,
      phi_fr_w1, phi_fr_b1, phi_fr_w2, phi_fr_b2,
      mto, mfr, 0, au, out_u, y, gw[2] / (float)NN, out_loss);
}

// Round 13
// 314.366 us; speedup vs baseline: 1.1128x; 1.1128x over previous
//
#include <hip/hip_runtime.h>

#define NN 100000
#define NE 800000
#define DD 16
#define ALPHA 0.1f

typedef _Float16 h2_t __attribute__((ext_vector_type(2)));
union U32H2 { unsigned u; h2_t h; };

__device__ __forceinline__ unsigned pack2h(float a, float b) {
  U32H2 v; v.h[0] = (_Float16)a; v.h[1] = (_Float16)b; return v.u;
}

// f32 += f16x2 . f16x2  (mixed-precision dot2); exact-math fallback if absent
__device__ __forceinline__ float dot2(unsigned a, unsigned b, float c) {
  U32H2 ua, ub; ua.u = a; ub.u = b;
#if __has_builtin(__builtin_amdgcn_fdot2)
  return __builtin_amdgcn_fdot2(ua.h, ub.h, c, false);
#else
  return fmaf((float)ua.h[0], (float)ub.h[0],
         fmaf((float)ua.h[1], (float)ub.h[1], c));
#endif
}

__device__ __forceinline__ void load16(const float* __restrict__ p, float* r) {
  float4 v0 = *(const float4*)(p + 0);
  float4 v1 = *(const float4*)(p + 4);
  float4 v2 = *(const float4*)(p + 8);
  float4 v3 = *(const float4*)(p + 12);
  r[0]=v0.x; r[1]=v0.y; r[2]=v0.z; r[3]=v0.w;
  r[4]=v1.x; r[5]=v1.y; r[6]=v1.z; r[7]=v1.w;
  r[8]=v2.x; r[9]=v2.y; r[10]=v2.z; r[11]=v2.w;
  r[12]=v3.x; r[13]=v3.y; r[14]=v3.z; r[15]=v3.w;
}

__device__ __forceinline__ void store16(float* __restrict__ p, const float* r) {
  *(float4*)(p + 0)  = make_float4(r[0], r[1], r[2], r[3]);
  *(float4*)(p + 4)  = make_float4(r[4], r[5], r[6], r[7]);
  *(float4*)(p + 8)  = make_float4(r[8], r[9], r[10], r[11]);
  *(float4*)(p + 12) = make_float4(r[12], r[13], r[14], r[15]);
}

// ---------------------------------------------------------------------------
// hist + rank over unified [in | out] histogram of length 2N
// (also zeroes out_loss — saves one memset dispatch)
// ---------------------------------------------------------------------------
__global__ __launch_bounds__(256) void hist_kernel(
    const int* __restrict__ ei, int* __restrict__ hist,
    int* __restrict__ rank_dst, int* __restrict__ rank_src,
    float* __restrict__ out_loss)
{
  int e = blockIdx.x * 256 + threadIdx.x;
  if (e == 0) *out_loss = 0.0f;
  if (e >= NE) return;
  int s = ei[e];
  int d = ei[NE + e];
  rank_dst[e] = atomicAdd(&hist[d], 1);
  rank_src[e] = atomicAdd(&hist[NN + s], 1);
}

// scan1 + fused degree-bucket histogram (reads each degree anyway)
__global__ __launch_bounds__(256) void scan1_kernel(
    const int* __restrict__ in, int* __restrict__ out, int* __restrict__ sums,
    int L, int* __restrict__ dhist)
{
  __shared__ int sh[256];
  __shared__ int lh[64];
  int t = threadIdx.x;
  if (t < 64) lh[t] = 0;
  int i0 = blockIdx.x * 1024 + t * 4;
  int v0 = (i0 + 0 < L) ? in[i0 + 0] : 0;
  int v1 = (i0 + 1 < L) ? in[i0 + 1] : 0;
  int v2 = (i0 + 2 < L) ? in[i0 + 2] : 0;
  int v3 = (i0 + 3 < L) ? in[i0 + 3] : 0;
  int tot = v0 + v1 + v2 + v3;
  sh[t] = tot;
  __syncthreads();
  if (i0 + 0 < L) atomicAdd(&lh[min(v0, 63)], 1);
  if (i0 + 1 < L) atomicAdd(&lh[min(v1, 63)], 1);
  if (i0 + 2 < L) atomicAdd(&lh[min(v2, 63)], 1);
  if (i0 + 3 < L) atomicAdd(&lh[min(v3, 63)], 1);
  int val = tot;
  for (int off = 1; off < 256; off <<= 1) {
    int x = (t >= off) ? sh[t - off] : 0;
    __syncthreads();
    val += x; sh[t] = val;
    __syncthreads();
  }
  if (t == 255) sums[blockIdx.x] = val;
  int run = val - tot;
  if (i0 + 0 < L) out[i0 + 0] = run; run += v0;
  if (i0 + 1 < L) out[i0 + 1] = run; run += v1;
  if (i0 + 2 < L) out[i0 + 2] = run; run += v2;
  if (i0 + 3 < L) out[i0 + 3] = run;
  if (t < 64 && lh[t]) atomicAdd(&dhist[t], lh[t]);
}

// scan2 + fused 64-bin exclusive scan of dhist (wave 0)
__global__ __launch_bounds__(256) void scan2_kernel(
    int* __restrict__ sums, int nb, int* __restrict__ out_total,
    int* __restrict__ dhist)
{
  __shared__ int sh[256];
  int t = threadIdx.x;
  int v = (t < nb) ? sums[t] : 0;
  sh[t] = v;
  __syncthreads();
  int val = v;
  for (int off = 1; off < 256; off <<= 1) {
    int x = (t >= off) ? sh[t - off] : 0;
    __syncthreads();
    val += x; sh[t] = val;
    __syncthreads();
  }
  if (t < nb) sums[t] = val - v;
  if (t == 255) *out_total = val;   // sentinel = 2*NE at base[2N]
  if (t < 64) {                     // wave 0: scan degree bins
    int dv = dhist[t];
    int dx = dv;
    #pragma unroll
    for (int off = 1; off < 64; off <<= 1) {
      int dy = __shfl_up(dx, off, 64);
      if (t >= off) dx += dy;
    }
    dhist[t] = dx - dv;             // exclusive base -> cursor for dperm
  }
}

__global__ __launch_bounds__(256) void scan3_kernel(
    int* __restrict__ out, const int* __restrict__ sums, int L)
{
  int i = blockIdx.x * 256 + threadIdx.x;
  if (i < L) out[i] += sums[i >> 10];
}

// atomic-free payload scatter into unified pay[2*NE] (8B packed entries)
// entry: {w0 = nbr:17 | e2f15:15, w1 = f16x2(e0,e1)}; nbr==0x1FFFF => self-loop
__global__ __launch_bounds__(256) void scatter_kernel(
    const int* __restrict__ ei, const float* __restrict__ ea, const float* __restrict__ a,
    const int* __restrict__ base,
    const int* __restrict__ rank_dst, const int* __restrict__ rank_src,
    uint2* __restrict__ pay, float2* __restrict__ pay_au)
{
  int e = blockIdx.x * 256 + threadIdx.x;
  if (e >= NE) return;
  int s = ei[e];
  int d = ei[NE + e];
  float e0 = ea[3 * (size_t)e], e1 = ea[3 * (size_t)e + 1], e2 = ea[3 * (size_t)e + 2];
  unsigned e01 = pack2h(e0, e1);
  U32H2 te; te.h[0] = (_Float16)e2; te.h[1] = (_Float16)0.0f;
  unsigned e2b = (te.u & 0xFFFFu) >> 1;         // 15-bit f16 (mantissa LSB dropped)
  int sl = (s == d);
  unsigned nb_d = sl ? 0x1FFFFu : (unsigned)s;
  unsigned nb_s = sl ? 0x1FFFFu : (unsigned)d;

  int pd = base[d] + rank_dst[e];
  pay[pd] = make_uint2(nb_d | (e2b << 17), e01);
  int ps = base[NN + s] + rank_src[e];
  pay[ps] = make_uint2(nb_s | (e2b << 17), e01);
  pay_au[ps - NE] = make_float2(__int_as_float(d), a[e]);
}

// degree-sorted permutation (after scatter: perm aliases rank_dst)
__global__ __launch_bounds__(256) void dperm_kernel(
    const int* __restrict__ base, int* __restrict__ dhist, int* __restrict__ perm)
{
  __shared__ int lh[64];
  __shared__ int lb[64];
  int t = threadIdx.x;
  if (t < 64) lh[t] = 0;
  __syncthreads();
  int g = blockIdx.x * 256 + t;
  int b = 0, r = 0;
  bool v = (g < 2 * NN);
  if (v) {
    int dg = base[g + 1] - base[g];
    b = min(dg, 63);
    r = atomicAdd(&lh[b], 1);
  }
  __syncthreads();
  if (t < 64 && lh[t]) lb[t] = atomicAdd(&dhist[t], lh[t]);
  __syncthreads();
  if (v) perm[lb[b] + r] = g;
}

// ---------------------------------------------------------------------------
// Gather: 8-lane subgroup per degree-sorted (node,dir) group.
// Neighbor + attr(e0,e1) matmul via f16 dot2 (weights pre-paired in LDS).
// ---------------------------------------------------------------------------
template<bool FIRST, bool WITH_AU>
__global__ __launch_bounds__(256) void gather_kernel(
    const float* __restrict__ h, const unsigned* __restrict__ hb,
    const uint2* __restrict__ pay, const int* __restrict__ base,
    const int* __restrict__ perm,
    const float* __restrict__ to_w1, const float* __restrict__ to_b1,
    const float* __restrict__ to_w2, const float* __restrict__ to_b2,
    const float* __restrict__ fr_w1, const float* __restrict__ fr_b1,
    const float* __restrict__ fr_w2, const float* __restrict__ fr_b2,
    float* __restrict__ mto, float* __restrict__ mfr, int gblocks,
    const float2* __restrict__ pay_au, const float* __restrict__ u,
    const float* __restrict__ y, float w, float* __restrict__ loss)
{
  if (WITH_AU && (int)blockIdx.x >= gblocks) {
    // ---- au_loss body ----
    __shared__ float ss[4];
    int n = (blockIdx.x - gblocks) * 256 + threadIdx.x;
    float acc = 0.0f;
    if (n < NN) {
      float auv = 0.0f;
      int beg = base[NN + n] - NE, end = base[NN + n + 1] - NE;
      for (int i = beg; i < end; ++i) {
        float2 q = pay_au[i];
        auv = fmaf(q.y, u[__float_as_int(q.x)], auv);
      }
      float dlt = auv - y[n];
      acc = dlt * dlt;
    }
    #pragma unroll
    for (int off = 32; off > 0; off >>= 1) acc += __shfl_down(acc, off);
    int lane = threadIdx.x & 63, wid = threadIdx.x >> 6;
    if (lane == 0) ss[wid] = acc;
    __syncthreads();
    if (threadIdx.x == 0) atomicAdd(loss, (ss[0] + ss[1] + ss[2] + ss[3]) * w);
    return;
  }

  // ---- gather body ----
  __shared__ float sw[1696];       // per half (848): w1[560] b1@560 w2@576 b2@832
  __shared__ unsigned w1h[2][144]; // f16 pairs: kp<8 rows {16+2kp,17+2kp}; kp=8 rows {32,33}
  __shared__ float p1buf[512];
  int t = threadIdx.x;
  for (int i = t; i < 560; i += 256) { sw[i] = to_w1[i]; sw[848 + i] = fr_w1[i]; }
  { int i = t;
    if (i < 256) { sw[576 + i] = to_w2[i]; sw[848 + 576 + i] = fr_w2[i]; }
    if (i < 16) {
      sw[560 + i] = to_b1[i];
      sw[832 + i] = to_b2[i];
      sw[848 + 560 + i] = fr_b1[i];
      sw[848 + 832 + i] = fr_b2[i];
    }
  }
  for (int i = t; i < 288; i += 256) {
    int dr = i / 144, idx = i % 144;
    int kp = idx >> 4, j = idx & 15;
    int r0 = (kp < 8) ? (16 + 2 * kp) : 32;
    const float* W = dr ? fr_w1 : to_w1;
    w1h[dr][idx] = pack2h(W[r0 * DD + j], W[(r0 + 1) * DD + j]);
  }
  __syncthreads();

  int sub = (blockIdx.x * 256 + t) >> 3;   // subgroup index (exact: 2N*8 threads)
  int l = t & 7;
  int g = perm[sub];                       // degree-sorted group
  int dir = (g >= NN) ? 1 : 0;             // 0 = mess_to, 1 = mess_from
  int n = g - (dir ? NN : 0);

  const float* w1 = sw + (dir ? 848 : 0);
  const float* b1 = w1 + 560;
  const float* w2 = w1 + 576;
  const float* b2 = w1 + 832;
  const unsigned* whn = w1h[dir];          // neighbor pairs [kp*16+j]
  const unsigned* wha = w1h[dir] + 128;    // attr rows 32,33 pairs [j]

  float p1v[DD];
  if (FIRST) {
    #pragma unroll
    for (int j = 0; j < DD; ++j) p1v[j] = b1[j];
  } else {
    // cooperative p1: lane l computes outputs 2l,2l+1 (32 FMA), exchange via LDS
    float hv[DD];
    load16(h + (size_t)n * DD, hv);
    int j0 = 2 * l;
    float pa = b1[j0], pb = b1[j0 + 1];
    #pragma unroll
    for (int k = 0; k < DD; ++k) {
      pa = fmaf(hv[k], w1[k * DD + j0], pa);
      pb = fmaf(hv[k], w1[k * DD + j0 + 1], pb);
    }
    p1buf[2 * t] = pa;
    p1buf[2 * t + 1] = pb;
    __syncthreads();
    const float* pbase = &p1buf[(t & ~7) * 2];
    #pragma unroll
    for (int j = 0; j < DD; ++j) p1v[j] = pbase[j];
  }

  float hs_[DD];
  #pragma unroll
  for (int j = 0; j < DD; ++j) hs_[j] = 0.0f;
  int cntv = 0;

  int beg = base[g], end = base[g + 1];
  for (int i = beg + l; i < end; i += 8) {
    uint2 q = pay[i];
    unsigned nb = q.x & 0x1FFFFu;
    if (nb != 0x1FFFFu) {
      unsigned e01 = q.y;
      U32H2 te; te.u = ((q.x >> 17) << 1) & 0xFFFFu;
      float e2f = (float)te.h[0];
      float hid[DD];
      #pragma unroll
      for (int j = 0; j < DD; ++j)
        hid[j] = fmaf(e2f, w1[34 * DD + j], dot2(e01, wha[j], p1v[j]));
      if (!FIRST) {
        uint4 qa = *(const uint4*)(hb + (size_t)nb * 8);
        uint4 qb = *(const uint4*)(hb + (size_t)nb * 8 + 4);
        unsigned hp[8] = {qa.x, qa.y, qa.z, qa.w, qb.x, qb.y, qb.z, qb.w};
        #pragma unroll
        for (int kp = 0; kp < 8; ++kp) {
          unsigned hv2 = hp[kp];
          #pragma unroll
          for (int j = 0; j < DD; ++j) hid[j] = dot2(hv2, whn[kp * 16 + j], hid[j]);
        }
      }
      #pragma unroll
      for (int j = 0; j < DD; ++j) hs_[j] += fmaxf(hid[j], 0.0f);
      ++cntv;
    }
  }

  // reduce across the 8-lane subgroup
  #pragma unroll
  for (int j = 0; j < DD; ++j) {
    hs_[j] += __shfl_xor(hs_[j], 1, 64);
    hs_[j] += __shfl_xor(hs_[j], 2, 64);
    hs_[j] += __shfl_xor(hs_[j], 4, 64);
  }
  cntv += __shfl_xor(cntv, 1, 64);
  cntv += __shfl_xor(cntv, 2, 64);
  cntv += __shfl_xor(cntv, 4, 64);

  // layer 2 once per group, feature-split: lane l emits outputs [2l, 2l+2)
  float c = (float)cntv;
  float m0 = c * b2[2 * l + 0];
  float m1 = c * b2[2 * l + 1];
  #pragma unroll
  for (int k = 0; k < DD; ++k) {
    float x = hs_[k];
    m0 = fmaf(x, w2[k * DD + 2 * l + 0], m0);
    m1 = fmaf(x, w2[k * DD + 2 * l + 1], m1);
  }
  float* dst = (dir ? mfr : mto) + (size_t)n * DD + 2 * l;
  *(float2*)dst = make_float2(m0, m1);
}

// ---------------------------------------------------------------------------
// Node kernel: h += ALPHA*psi([h,mto,mfr,prb]); u = dec(h); hb = f16(h)
// FIRST=true: h == 0 -> skip h load and its 16 rows.
// ---------------------------------------------------------------------------
template<bool FIRST>
__global__ __launch_bounds__(256) void node_kernel(
    float* __restrict__ h, unsigned* __restrict__ hb,
    const float* __restrict__ mto, const float* __restrict__ mfr,
    const float* __restrict__ prb,
    const float* __restrict__ psi_w1, const float* __restrict__ psi_b1,
    const float* __restrict__ psi_w2, const float* __restrict__ psi_b2,
    const float* __restrict__ dec_w1, const float* __restrict__ dec_b1,
    const float* __restrict__ dec_w2, const float* __restrict__ dec_b2,
    float* __restrict__ u)
{
  __shared__ float sw[1361];
  for (int i = threadIdx.x; i < 784; i += 256) sw[i] = psi_w1[i];
  { int i = threadIdx.x;
    if (i < 256) { sw[800 + i] = psi_w2[i]; sw[1072 + i] = dec_w1[i]; }
    if (i < 16) {
      sw[784 + i] = psi_b1[i];
      sw[1056 + i] = psi_b2[i];
      sw[1328 + i] = dec_b1[i];
      sw[1344 + i] = dec_w2[i];
    }
    if (i == 0) sw[1360] = dec_b2[0];
  }
  __syncthreads();

  int n = blockIdx.x * 256 + threadIdx.x;
  if (n >= NN) return;

  float hv[DD], mt[DD], mf[DD];
  if (!FIRST) {
    load16(h + (size_t)n * DD, hv);
  } else {
    for (int j = 0; j < DD; ++j) hv[j] = 0.0f;
  }
  load16(mto + (size_t)n * DD, mt);
  load16(mfr + (size_t)n * DD, mf);
  float p = prb[n];

  float hid[DD];
  #pragma unroll
  for (int j = 0; j < DD; ++j) hid[j] = sw[784 + j];
  if (!FIRST) {
    #pragma unroll
    for (int i = 0; i < DD; ++i) {
      float x = hv[i];
      #pragma unroll
      for (int j = 0; j < DD; ++j) hid[j] = fmaf(x, sw[i * DD + j], hid[j]);
    }
  }
  #pragma unroll
  for (int i = 0; i < DD; ++i) {
    float x = mt[i];
    #pragma unroll
    for (int j = 0; j < DD; ++j) hid[j] = fmaf(x, sw[(DD + i) * DD + j], hid[j]);
  }
  #pragma unroll
  for (int i = 0; i < DD; ++i) {
    float x = mf[i];
    #pragma unroll
    for (int j = 0; j < DD; ++j) hid[j] = fmaf(x, sw[(2 * DD + i) * DD + j], hid[j]);
  }
  #pragma unroll
  for (int j = 0; j < DD; ++j) hid[j] = fmaf(p, sw[48 * DD + j], hid[j]);
  #pragma unroll
  for (int j = 0; j < DD; ++j) hid[j] = fmaxf(hid[j], 0.0f);

  float hnew[DD];
  #pragma unroll
  for (int j = 0; j < DD; ++j) hnew[j] = sw[1056 + j];
  #pragma unroll
  for (int i = 0; i < DD; ++i) {
    float x = hid[i];
    #pragma unroll
    for (int j = 0; j < DD; ++j) hnew[j] = fmaf(x, sw[800 + i * DD + j], hnew[j]);
  }
  #pragma unroll
  for (int j = 0; j < DD; ++j) hnew[j] = fmaf(ALPHA, hnew[j], hv[j]);
  store16(h + (size_t)n * DD, hnew);

  uint4 pa, pb;
  pa.x = pack2h(hnew[0],  hnew[1]);
  pa.y = pack2h(hnew[2],  hnew[3]);
  pa.z = pack2h(hnew[4],  hnew[5]);
  pa.w = pack2h(hnew[6],  hnew[7]);
  pb.x = pack2h(hnew[8],  hnew[9]);
  pb.y = pack2h(hnew[10], hnew[11]);
  pb.z = pack2h(hnew[12], hnew[13]);
  pb.w = pack2h(hnew[14], hnew[15]);
  *(uint4*)(hb + (size_t)n * 8)     = pa;
  *(uint4*)(hb + (size_t)n * 8 + 4) = pb;

  float hid2[DD];
  #pragma unroll
  for (int j = 0; j < DD; ++j) hid2[j] = sw[1328 + j];
  #pragma unroll
  for (int i = 0; i < DD; ++i) {
    float x = hnew[i];
    #pragma unroll
    for (int j = 0; j < DD; ++j) hid2[j] = fmaf(x, sw[1072 + i * DD + j], hid2[j]);
  }
  float uo = sw[1360];
  #pragma unroll
  for (int i = 0; i < DD; ++i) uo += fmaxf(hid2[i], 0.0f) * sw[1344 + i];
  u[n] = uo;
}

extern "C" void kernel_launch(void* const* d_in, const int* in_sizes, int n_in,
                              void* d_out, int out_size, void* d_ws, size_t ws_size,
                              hipStream_t stream) {
  const int*   ei        = (const int*)d_in[0];
  const float* ea        = (const float*)d_in[1];
  const float* a_ij      = (const float*)d_in[2];
  const float* prb       = (const float*)d_in[3];
  const float* y         = (const float*)d_in[5];
  const float* phi_to_w1 = (const float*)d_in[6];
  const float* phi_to_b1 = (const float*)d_in[7];
  const float* phi_to_w2 = (const float*)d_in[8];
  const float* phi_to_b2 = (const float*)d_in[9];
  const float* phi_fr_w1 = (const float*)d_in[10];
  const float* phi_fr_b1 = (const float*)d_in[11];
  const float* phi_fr_w2 = (const float*)d_in[12];
  const float* phi_fr_b2 = (const float*)d_in[13];
  const float* psi_w1    = (const float*)d_in[14];
  const float* psi_b1    = (const float*)d_in[15];
  const float* psi_w2    = (const float*)d_in[16];
  const float* psi_b2    = (const float*)d_in[17];
  const float* dec_w1    = (const float*)d_in[18];
  const float* dec_b1    = (const float*)d_in[19];
  const float* dec_w2    = (const float*)d_in[20];
  const float* dec_b2    = (const float*)d_in[21];

  float* out_u    = (float*)d_out;
  float* out_loss = out_u + NN;

  char* wp = (char*)d_ws;
  auto carve = [&](size_t bytes) { void* p = (void*)wp; wp += (bytes + 15) & ~(size_t)15; return p; };
  uint2*    pay    = (uint2*)carve((size_t)2 * NE * 8);     // packed [dst-sorted | src-sorted]
  float2*   pay_au = (float2*)carve((size_t)NE * 8);
  float*    h      = (float*)carve((size_t)NN * DD * 4);
  unsigned* hb16   = (unsigned*)carve((size_t)NN * 8 * 4);  // f16x2 pairs, 8 u32/node
  float*    mto    = (float*)carve((size_t)NN * DD * 4);
  float*    mfr    = (float*)carve((size_t)NN * DD * 4);
  int*  rank_dst   = (int*)carve((size_t)NE * 4);
  int*  rank_src   = (int*)carve((size_t)NE * 4);
  int*  base       = (int*)carve((size_t)(2 * NN + 1) * 4);
  int*  hist       = (int*)carve((size_t)2 * NN * 4);
  int*  dhist      = (int*)carve(64 * 4);                   // contiguous after hist
  int*  sums       = (int*)carve(256 * 4);
  int*  perm       = rank_dst;   // alias: rank_dst dead after scatter

  hipMemsetAsync(hist, 0, ((size_t)2 * NN + 64) * 4, stream);  // hist + dhist

  const int EB  = (NE + 255) / 256;             // 3125
  const int NB  = (NN + 255) / 256;             // 391
  const int L2N = 2 * NN;                       // 200000
  const int SB1 = (L2N + 1023) / 1024;          // 196
  const int SB3 = (L2N + 255) / 256;            // 782
  const int GB8 = (L2N * 8) / 256;              // 6250 (exact)

  hist_kernel<<<EB, 256, 0, stream>>>(ei, hist, rank_dst, rank_src, out_loss);
  scan1_kernel<<<SB1, 256, 0, stream>>>(hist, base, sums, L2N, dhist);
  scan2_kernel<<<1, 256, 0, stream>>>(sums, SB1, base + L2N, dhist);
  scan3_kernel<<<SB3, 256, 0, stream>>>(base, sums, L2N);
  scatter_kernel<<<EB, 256, 0, stream>>>(ei, ea, a_ij, base, rank_dst, rank_src,
                                         pay, pay_au);
  dperm_kernel<<<SB3, 256, 0, stream>>>(base, dhist, perm);

  const float gw[3] = {0.81f, 0.9f, 1.0f};  // gamma^(K-1-t)

  // t = 0 (h == 0)
  gather_kernel<true, false><<<GB8, 256, 0, stream>>>(
      h, hb16, pay, base, perm,
      phi_to_w1, phi_to_b1, phi_to_w2, phi_to_b2,
      phi_fr_w1, phi_fr_b1, phi_fr_w2, phi_fr_b2,
      mto, mfr, GB8, pay_au, out_u, y, 0.0f, out_loss);
  node_kernel<true><<<NB, 256, 0, stream>>>(
      h, hb16, mto, mfr, prb,
      psi_w1, psi_b1, psi_w2, psi_b2,
      dec_w1, dec_b1, dec_w2, dec_b2, out_u);

  // t = 1, 2: gather(t) fused with au_loss(t-1)
  for (int t = 1; t < 3; ++t) {
    gather_kernel<false, true><<<GB8 + NB, 256, 0, stream>>>(
        h, hb16, pay, base, perm,
        phi_to_w1 + t * 560, phi_to_b1 + t * 16, phi_to_w2 + t * 256, phi_to_b2 + t * 16,
        phi_fr_w1 + t * 560, phi_fr_b1 + t * 16, phi_fr_w2 + t * 256, phi_fr_b2 + t * 16,
        mto, mfr, GB8, pay_au, out_u, y, gw[t - 1] / (float)NN, out_loss);
    node_kernel<false><<<NB, 256, 0, stream>>>(
        h, hb16, mto, mfr, prb,
        psi_w1 + t * 784, psi_b1 + t * 16, psi_w2 + t * 256, psi_b2 + t * 16,
        dec_w1 + t * 256, dec_b1 + t * 16, dec_w2 + t * 16, dec_b2 + t, out_u);
  }

  // final residual loss (t = 2's u)
  gather_kernel<false, true><<<NB, 256, 0, stream>>>(
      h, hb16, pay, base, perm,
      phi_to_w1, phi_to_b1, phi_to_w2, phi_to_b2,
      phi_fr_w1, phi_fr_b1, phi_fr_w2, phi_fr_b2,
      mto, mfr, 0, pay_au, out_u, y, gw[2] / (float)NN, out_loss);
}

// Round 14
// 314.243 us; speedup vs baseline: 1.1132x; 1.0004x over previous
//
#include <hip/hip_runtime.h>

#define NN 100000
#define NE 800000
#define DD 16
#define ALPHA 0.1f

typedef _Float16 h2_t __attribute__((ext_vector_type(2)));
union U32H2 { unsigned u; h2_t h; };

__device__ __forceinline__ unsigned pack2h(float a, float b) {
  U32H2 v; v.h[0] = (_Float16)a; v.h[1] = (_Float16)b; return v.u;
}

// f32 += f16x2 . f16x2  (mixed-precision dot2); exact-math fallback if absent
__device__ __forceinline__ float dot2(unsigned a, unsigned b, float c) {
  U32H2 ua, ub; ua.u = a; ub.u = b;
#if __has_builtin(__builtin_amdgcn_fdot2)
  return __builtin_amdgcn_fdot2(ua.h, ub.h, c, false);
#else
  return fmaf((float)ua.h[0], (float)ub.h[0],
         fmaf((float)ua.h[1], (float)ub.h[1], c));
#endif
}

__device__ __forceinline__ void load16(const float* __restrict__ p, float* r) {
  float4 v0 = *(const float4*)(p + 0);
  float4 v1 = *(const float4*)(p + 4);
  float4 v2 = *(const float4*)(p + 8);
  float4 v3 = *(const float4*)(p + 12);
  r[0]=v0.x; r[1]=v0.y; r[2]=v0.z; r[3]=v0.w;
  r[4]=v1.x; r[5]=v1.y; r[6]=v1.z; r[7]=v1.w;
  r[8]=v2.x; r[9]=v2.y; r[10]=v2.z; r[11]=v2.w;
  r[12]=v3.x; r[13]=v3.y; r[14]=v3.z; r[15]=v3.w;
}

__device__ __forceinline__ void store16(float* __restrict__ p, const float* r) {
  *(float4*)(p + 0)  = make_float4(r[0], r[1], r[2], r[3]);
  *(float4*)(p + 4)  = make_float4(r[4], r[5], r[6], r[7]);
  *(float4*)(p + 8)  = make_float4(r[8], r[9], r[10], r[11]);
  *(float4*)(p + 12) = make_float4(r[12], r[13], r[14], r[15]);
}

// ---------------------------------------------------------------------------
// hist + rank over unified [in | out] histogram of length 2N
// (also zeroes out_loss — saves one memset dispatch)
// ---------------------------------------------------------------------------
__global__ __launch_bounds__(256) void hist_kernel(
    const int* __restrict__ ei, int* __restrict__ hist,
    int* __restrict__ rank_dst, int* __restrict__ rank_src,
    float* __restrict__ out_loss)
{
  int e = blockIdx.x * 256 + threadIdx.x;
  if (e == 0) *out_loss = 0.0f;
  if (e >= NE) return;
  int s = ei[e];
  int d = ei[NE + e];
  rank_dst[e] = atomicAdd(&hist[d], 1);
  rank_src[e] = atomicAdd(&hist[NN + s], 1);
}

// scan1 + fused degree-bucket histogram (reads each degree anyway)
__global__ __launch_bounds__(256) void scan1_kernel(
    const int* __restrict__ in, int* __restrict__ out, int* __restrict__ sums,
    int L, int* __restrict__ dhist)
{
  __shared__ int sh[256];
  __shared__ int lh[64];
  int t = threadIdx.x;
  if (t < 64) lh[t] = 0;
  int i0 = blockIdx.x * 1024 + t * 4;
  int v0 = (i0 + 0 < L) ? in[i0 + 0] : 0;
  int v1 = (i0 + 1 < L) ? in[i0 + 1] : 0;
  int v2 = (i0 + 2 < L) ? in[i0 + 2] : 0;
  int v3 = (i0 + 3 < L) ? in[i0 + 3] : 0;
  int tot = v0 + v1 + v2 + v3;
  sh[t] = tot;
  __syncthreads();
  if (i0 + 0 < L) atomicAdd(&lh[min(v0, 63)], 1);
  if (i0 + 1 < L) atomicAdd(&lh[min(v1, 63)], 1);
  if (i0 + 2 < L) atomicAdd(&lh[min(v2, 63)], 1);
  if (i0 + 3 < L) atomicAdd(&lh[min(v3, 63)], 1);
  int val = tot;
  for (int off = 1; off < 256; off <<= 1) {
    int x = (t >= off) ? sh[t - off] : 0;
    __syncthreads();
    val += x; sh[t] = val;
    __syncthreads();
  }
  if (t == 255) sums[blockIdx.x] = val;
  int run = val - tot;
  if (i0 + 0 < L) out[i0 + 0] = run; run += v0;
  if (i0 + 1 < L) out[i0 + 1] = run; run += v1;
  if (i0 + 2 < L) out[i0 + 2] = run; run += v2;
  if (i0 + 3 < L) out[i0 + 3] = run;
  if (t < 64 && lh[t]) atomicAdd(&dhist[t], lh[t]);
}

// scan2 + fused 64-bin exclusive scan of dhist (wave 0)
__global__ __launch_bounds__(256) void scan2_kernel(
    int* __restrict__ sums, int nb, int* __restrict__ out_total,
    int* __restrict__ dhist)
{
  __shared__ int sh[256];
  int t = threadIdx.x;
  int v = (t < nb) ? sums[t] : 0;
  sh[t] = v;
  __syncthreads();
  int val = v;
  for (int off = 1; off < 256; off <<= 1) {
    int x = (t >= off) ? sh[t - off] : 0;
    __syncthreads();
    val += x; sh[t] = val;
    __syncthreads();
  }
  if (t < nb) sums[t] = val - v;
  if (t == 255) *out_total = val;   // sentinel = 2*NE at base[2N]
  if (t < 64) {                     // wave 0: scan degree bins
    int dv = dhist[t];
    int dx = dv;
    #pragma unroll
    for (int off = 1; off < 64; off <<= 1) {
      int dy = __shfl_up(dx, off, 64);
      if (t >= off) dx += dy;
    }
    dhist[t] = dx - dv;             // exclusive base -> cursor for dperm
  }
}

__global__ __launch_bounds__(256) void scan3_kernel(
    int* __restrict__ out, const int* __restrict__ sums, int L)
{
  int i = blockIdx.x * 256 + threadIdx.x;
  if (i < L) out[i] += sums[i >> 10];
}

// atomic-free payload scatter into unified pay[2*NE] (8B packed entries)
// entry: {w0 = nbr:17 | e2f15:15, w1 = f16x2(e0,e1)}; nbr==0x1FFFF => self-loop
__global__ __launch_bounds__(256) void scatter_kernel(
    const int* __restrict__ ei, const float* __restrict__ ea, const float* __restrict__ a,
    const int* __restrict__ base,
    const int* __restrict__ rank_dst, const int* __restrict__ rank_src,
    uint2* __restrict__ pay, float2* __restrict__ pay_au)
{
  int e = blockIdx.x * 256 + threadIdx.x;
  if (e >= NE) return;
  int s = ei[e];
  int d = ei[NE + e];
  float e0 = ea[3 * (size_t)e], e1 = ea[3 * (size_t)e + 1], e2 = ea[3 * (size_t)e + 2];
  unsigned e01 = pack2h(e0, e1);
  U32H2 te; te.h[0] = (_Float16)e2; te.h[1] = (_Float16)0.0f;
  unsigned e2b = (te.u & 0xFFFFu) >> 1;         // 15-bit f16 (mantissa LSB dropped)
  int sl = (s == d);
  unsigned nb_d = sl ? 0x1FFFFu : (unsigned)s;
  unsigned nb_s = sl ? 0x1FFFFu : (unsigned)d;

  int pd = base[d] + rank_dst[e];
  pay[pd] = make_uint2(nb_d | (e2b << 17), e01);
  int ps = base[NN + s] + rank_src[e];
  pay[ps] = make_uint2(nb_s | (e2b << 17), e01);
  pay_au[ps - NE] = make_float2(__int_as_float(d), a[e]);
}

// degree-sorted permutation (after scatter: perm aliases rank_dst)
__global__ __launch_bounds__(256) void dperm_kernel(
    const int* __restrict__ base, int* __restrict__ dhist, int* __restrict__ perm)
{
  __shared__ int lh[64];
  __shared__ int lb[64];
  int t = threadIdx.x;
  if (t < 64) lh[t] = 0;
  __syncthreads();
  int g = blockIdx.x * 256 + t;
  int b = 0, r = 0;
  bool v = (g < 2 * NN);
  if (v) {
    int dg = base[g + 1] - base[g];
    b = min(dg, 63);
    r = atomicAdd(&lh[b], 1);
  }
  __syncthreads();
  if (t < 64 && lh[t]) lb[t] = atomicAdd(&dhist[t], lh[t]);
  __syncthreads();
  if (v) perm[lb[b] + r] = g;
}

// ---------------------------------------------------------------------------
// Gather: 8-lane subgroup per degree-sorted (node,dir) group.
// All LDS weight reads forced wide (uint4/float4/float2 = ds_read_b128/b64).
// ---------------------------------------------------------------------------
template<bool FIRST, bool WITH_AU>
__global__ __launch_bounds__(256) void gather_kernel(
    const float* __restrict__ h, const unsigned* __restrict__ hb,
    const uint2* __restrict__ pay, const int* __restrict__ base,
    const int* __restrict__ perm,
    const float* __restrict__ to_w1, const float* __restrict__ to_b1,
    const float* __restrict__ to_w2, const float* __restrict__ to_b2,
    const float* __restrict__ fr_w1, const float* __restrict__ fr_b1,
    const float* __restrict__ fr_w2, const float* __restrict__ fr_b2,
    float* __restrict__ mto, float* __restrict__ mfr, int gblocks,
    const float2* __restrict__ pay_au, const float* __restrict__ u,
    const float* __restrict__ y, float w, float* __restrict__ loss)
{
  if (WITH_AU && (int)blockIdx.x >= gblocks) {
    // ---- au_loss body ----
    __shared__ float ss[4];
    int n = (blockIdx.x - gblocks) * 256 + threadIdx.x;
    float acc = 0.0f;
    if (n < NN) {
      float auv = 0.0f;
      int beg = base[NN + n] - NE, end = base[NN + n + 1] - NE;
      for (int i = beg; i < end; ++i) {
        float2 q = pay_au[i];
        auv = fmaf(q.y, u[__float_as_int(q.x)], auv);
      }
      float dlt = auv - y[n];
      acc = dlt * dlt;
    }
    #pragma unroll
    for (int off = 32; off > 0; off >>= 1) acc += __shfl_down(acc, off);
    int lane = threadIdx.x & 63, wid = threadIdx.x >> 6;
    if (lane == 0) ss[wid] = acc;
    __syncthreads();
    if (threadIdx.x == 0) atomicAdd(loss, (ss[0] + ss[1] + ss[2] + ss[3]) * w);
    return;
  }

  // ---- gather body ----
  __shared__ __align__(16) float sw[1696];       // per half (848): w1[560] b1@560 w2@576 b2@832
  __shared__ __align__(16) unsigned w1h[2][144]; // f16 pairs: kp<8 rows {16+2kp,17+2kp}; kp=8 rows {32,33}
  __shared__ __align__(16) float p1buf[512];
  int t = threadIdx.x;
  for (int i = t; i < 560; i += 256) { sw[i] = to_w1[i]; sw[848 + i] = fr_w1[i]; }
  { int i = t;
    if (i < 256) { sw[576 + i] = to_w2[i]; sw[848 + 576 + i] = fr_w2[i]; }
    if (i < 16) {
      sw[560 + i] = to_b1[i];
      sw[832 + i] = to_b2[i];
      sw[848 + 560 + i] = fr_b1[i];
      sw[848 + 832 + i] = fr_b2[i];
    }
  }
  for (int i = t; i < 288; i += 256) {
    int dr = i / 144, idx = i % 144;
    int kp = idx >> 4, j = idx & 15;
    int r0 = (kp < 8) ? (16 + 2 * kp) : 32;
    const float* W = dr ? fr_w1 : to_w1;
    w1h[dr][idx] = pack2h(W[r0 * DD + j], W[(r0 + 1) * DD + j]);
  }
  __syncthreads();

  int sub = (blockIdx.x * 256 + t) >> 3;   // subgroup index (exact: 2N*8 threads)
  int l = t & 7;
  int g = perm[sub];                       // degree-sorted group
  int dir = (g >= NN) ? 1 : 0;             // 0 = mess_to, 1 = mess_from
  int n = g - (dir ? NN : 0);

  const float* w1 = sw + (dir ? 848 : 0);
  const float* b1 = w1 + 560;
  const float* w2 = w1 + 576;
  const float* b2 = w1 + 832;
  const uint4*  whn4 = (const uint4*)(w1h[dir]);        // nbr pairs, [kp*4+m]
  const uint4*  wha4 = (const uint4*)(w1h[dir] + 128);  // attr rows 32,33
  const float4* wa34 = (const float4*)(w1 + 34 * DD);   // attr row 34 (f32)

  float p1v[DD];
  if (FIRST) {
    #pragma unroll
    for (int j = 0; j < DD; ++j) p1v[j] = b1[j];
  } else {
    // cooperative p1: lane l computes outputs 2l,2l+1 (32 FMA), exchange via LDS
    float hv[DD];
    load16(h + (size_t)n * DD, hv);
    int j0 = 2 * l;
    const float2* b1p = (const float2*)b1;
    float2 pp = b1p[l];
    #pragma unroll
    for (int k = 0; k < DD; ++k) {
      float2 wk = *(const float2*)(w1 + k * DD + j0);
      pp.x = fmaf(hv[k], wk.x, pp.x);
      pp.y = fmaf(hv[k], wk.y, pp.y);
    }
    *(float2*)(p1buf + 2 * t) = pp;
    __syncthreads();
    const float4* pbase = (const float4*)&p1buf[(t & ~7) * 2];
    #pragma unroll
    for (int m = 0; m < 4; ++m) {
      float4 pv = pbase[m];
      p1v[4 * m + 0] = pv.x; p1v[4 * m + 1] = pv.y;
      p1v[4 * m + 2] = pv.z; p1v[4 * m + 3] = pv.w;
    }
  }

  float hs_[DD];
  #pragma unroll
  for (int j = 0; j < DD; ++j) hs_[j] = 0.0f;
  int cntv = 0;

  int beg = base[g], end = base[g + 1];
  for (int i = beg + l; i < end; i += 8) {
    uint2 q = pay[i];
    unsigned nb = q.x & 0x1FFFFu;
    if (nb != 0x1FFFFu) {
      unsigned e01 = q.y;
      U32H2 te; te.u = ((q.x >> 17) << 1) & 0xFFFFu;
      float e2f = (float)te.h[0];
      float hid[DD];
      #pragma unroll
      for (int m = 0; m < 4; ++m) {
        uint4  wq = wha4[m];
        float4 wa = wa34[m];
        hid[4 * m + 0] = fmaf(e2f, wa.x, dot2(e01, wq.x, p1v[4 * m + 0]));
        hid[4 * m + 1] = fmaf(e2f, wa.y, dot2(e01, wq.y, p1v[4 * m + 1]));
        hid[4 * m + 2] = fmaf(e2f, wa.z, dot2(e01, wq.z, p1v[4 * m + 2]));
        hid[4 * m + 3] = fmaf(e2f, wa.w, dot2(e01, wq.w, p1v[4 * m + 3]));
      }
      if (!FIRST) {
        uint4 qa = *(const uint4*)(hb + (size_t)nb * 8);
        uint4 qb = *(const uint4*)(hb + (size_t)nb * 8 + 4);
        unsigned hp[8] = {qa.x, qa.y, qa.z, qa.w, qb.x, qb.y, qb.z, qb.w};
        #pragma unroll
        for (int kp = 0; kp < 8; ++kp) {
          unsigned hv2 = hp[kp];
          #pragma unroll
          for (int m = 0; m < 4; ++m) {
            uint4 wq = whn4[kp * 4 + m];
            hid[4 * m + 0] = dot2(hv2, wq.x, hid[4 * m + 0]);
            hid[4 * m + 1] = dot2(hv2, wq.y, hid[4 * m + 1]);
            hid[4 * m + 2] = dot2(hv2, wq.z, hid[4 * m + 2]);
            hid[4 * m + 3] = dot2(hv2, wq.w, hid[4 * m + 3]);
          }
        }
      }
      #pragma unroll
      for (int j = 0; j < DD; ++j) hs_[j] += fmaxf(hid[j], 0.0f);
      ++cntv;
    }
  }

  // reduce across the 8-lane subgroup
  #pragma unroll
  for (int j = 0; j < DD; ++j) {
    hs_[j] += __shfl_xor(hs_[j], 1, 64);
    hs_[j] += __shfl_xor(hs_[j], 2, 64);
    hs_[j] += __shfl_xor(hs_[j], 4, 64);
  }
  cntv += __shfl_xor(cntv, 1, 64);
  cntv += __shfl_xor(cntv, 2, 64);
  cntv += __shfl_xor(cntv, 4, 64);

  // layer 2 once per group, feature-split: lane l emits outputs [2l, 2l+2)
  float c = (float)cntv;
  const float2* b2p = (const float2*)b2;
  float2 bb = b2p[l];
  float m0 = c * bb.x;
  float m1 = c * bb.y;
  #pragma unroll
  for (int k = 0; k < DD; ++k) {
    float2 wk = *(const float2*)(w2 + k * DD + 2 * l);
    float x = hs_[k];
    m0 = fmaf(x, wk.x, m0);
    m1 = fmaf(x, wk.y, m1);
  }
  float* dst = (dir ? mfr : mto) + (size_t)n * DD + 2 * l;
  *(float2*)dst = make_float2(m0, m1);
}

// ---------------------------------------------------------------------------
// Node kernel: h += ALPHA*psi([h,mto,mfr,prb]); u = dec(h); hb = f16(h)
// FIRST=true: h == 0 -> skip h load and its 16 rows.
// ---------------------------------------------------------------------------
template<bool FIRST>
__global__ __launch_bounds__(256) void node_kernel(
    float* __restrict__ h, unsigned* __restrict__ hb,
    const float* __restrict__ mto, const float* __restrict__ mfr,
    const float* __restrict__ prb,
    const float* __restrict__ psi_w1, const float* __restrict__ psi_b1,
    const float* __restrict__ psi_w2, const float* __restrict__ psi_b2,
    const float* __restrict__ dec_w1, const float* __restrict__ dec_b1,
    const float* __restrict__ dec_w2, const float* __restrict__ dec_b2,
    float* __restrict__ u)
{
  __shared__ __align__(16) float sw[1364];
  for (int i = threadIdx.x; i < 784; i += 256) sw[i] = psi_w1[i];
  { int i = threadIdx.x;
    if (i < 256) { sw[800 + i] = psi_w2[i]; sw[1072 + i] = dec_w1[i]; }
    if (i < 16) {
      sw[784 + i] = psi_b1[i];
      sw[1056 + i] = psi_b2[i];
      sw[1328 + i] = dec_b1[i];
      sw[1344 + i] = dec_w2[i];
    }
    if (i == 0) sw[1360] = dec_b2[0];
  }
  __syncthreads();

  int n = blockIdx.x * 256 + threadIdx.x;
  if (n >= NN) return;

  float hv[DD], mt[DD], mf[DD];
  if (!FIRST) {
    load16(h + (size_t)n * DD, hv);
  } else {
    for (int j = 0; j < DD; ++j) hv[j] = 0.0f;
  }
  load16(mto + (size_t)n * DD, mt);
  load16(mfr + (size_t)n * DD, mf);
  float p = prb[n];

  float hid[DD];
  #pragma unroll
  for (int j = 0; j < DD; ++j) hid[j] = sw[784 + j];
  if (!FIRST) {
    #pragma unroll
    for (int i = 0; i < DD; ++i) {
      float x = hv[i];
      #pragma unroll
      for (int j = 0; j < DD; ++j) hid[j] = fmaf(x, sw[i * DD + j], hid[j]);
    }
  }
  #pragma unroll
  for (int i = 0; i < DD; ++i) {
    float x = mt[i];
    #pragma unroll
    for (int j = 0; j < DD; ++j) hid[j] = fmaf(x, sw[(DD + i) * DD + j], hid[j]);
  }
  #pragma unroll
  for (int i = 0; i < DD; ++i) {
    float x = mf[i];
    #pragma unroll
    for (int j = 0; j < DD; ++j) hid[j] = fmaf(x, sw[(2 * DD + i) * DD + j], hid[j]);
  }
  #pragma unroll
  for (int j = 0; j < DD; ++j) hid[j] = fmaf(p, sw[48 * DD + j], hid[j]);
  #pragma unroll
  for (int j = 0; j < DD; ++j) hid[j] = fmaxf(hid[j], 0.0f);

  float hnew[DD];
  #pragma unroll
  for (int j = 0; j < DD; ++j) hnew[j] = sw[1056 + j];
  #pragma unroll
  for (int i = 0; i < DD; ++i) {
    float x = hid[i];
    #pragma unroll
    for (int j = 0; j < DD; ++j) hnew[j] = fmaf(x, sw[800 + i * DD + j], hnew[j]);
  }
  #pragma unroll
  for (int j = 0; j < DD; ++j) hnew[j] = fmaf(ALPHA, hnew[j], hv[j]);
  store16(h + (size_t)n * DD, hnew);

  uint4 pa, pb;
  pa.x = pack2h(hnew[0],  hnew[1]);
  pa.y = pack2h(hnew[2],  hnew[3]);
  pa.z = pack2h(hnew[4],  hnew[5]);
  pa.w = pack2h(hnew[6],  hnew[7]);
  pb.x = pack2h(hnew[8],  hnew[9]);
  pb.y = pack2h(hnew[10], hnew[11]);
  pb.z = pack2h(hnew[12], hnew[13]);
  pb.w = pack2h(hnew[14], hnew[15]);
  *(uint4*)(hb + (size_t)n * 8)     = pa;
  *(uint4*)(hb + (size_t)n * 8 + 4) = pb;

  float hid2[DD];
  #pragma unroll
  for (int j = 0; j < DD; ++j) hid2[j] = sw[1328 + j];
  #pragma unroll
  for (int i = 0; i < DD; ++i) {
    float x = hnew[i];
    #pragma unroll
    for (int j = 0; j < DD; ++j) hid2[j] = fmaf(x, sw[1072 + i * DD + j], hid2[j]);
  }
  float uo = sw[1360];
  #pragma unroll
  for (int i = 0; i < DD; ++i) uo += fmaxf(hid2[i], 0.0f) * sw[1344 + i];
  u[n] = uo;
}

extern "C" void kernel_launch(void* const* d_in, const int* in_sizes, int n_in,
                              void* d_out, int out_size, void* d_ws, size_t ws_size,
                              hipStream_t stream) {
  const int*   ei        = (const int*)d_in[0];
  const float* ea        = (const float*)d_in[1];
  const float* a_ij      = (const float*)d_in[2];
  const float* prb       = (const float*)d_in[3];
  const float* y         = (const float*)d_in[5];
  const float* phi_to_w1 = (const float*)d_in[6];
  const float* phi_to_b1 = (const float*)d_in[7];
  const float* phi_to_w2 = (const float*)d_in[8];
  const float* phi_to_b2 = (const float*)d_in[9];
  const float* phi_fr_w1 = (const float*)d_in[10];
  const float* phi_fr_b1 = (const float*)d_in[11];
  const float* phi_fr_w2 = (const float*)d_in[12];
  const float* phi_fr_b2 = (const float*)d_in[13];
  const float* psi_w1    = (const float*)d_in[14];
  const float* psi_b1    = (const float*)d_in[15];
  const float* psi_w2    = (const float*)d_in[16];
  const float* psi_b2    = (const float*)d_in[17];
  const float* dec_w1    = (const float*)d_in[18];
  const float* dec_b1    = (const float*)d_in[19];
  const float* dec_w2    = (const float*)d_in[20];
  const float* dec_b2    = (const float*)d_in[21];

  float* out_u    = (float*)d_out;
  float* out_loss = out_u + NN;

  char* wp = (char*)d_ws;
  auto carve = [&](size_t bytes) { void* p = (void*)wp; wp += (bytes + 15) & ~(size_t)15; return p; };
  uint2*    pay    = (uint2*)carve((size_t)2 * NE * 8);     // packed [dst-sorted | src-sorted]
  float2*   pay_au = (float2*)carve((size_t)NE * 8);
  float*    h      = (float*)carve((size_t)NN * DD * 4);
  unsigned* hb16   = (unsigned*)carve((size_t)NN * 8 * 4);  // f16x2 pairs, 8 u32/node
  float*    mto    = (float*)carve((size_t)NN * DD * 4);
  float*    mfr    = (float*)carve((size_t)NN * DD * 4);
  int*  rank_dst   = (int*)carve((size_t)NE * 4);
  int*  rank_src   = (int*)carve((size_t)NE * 4);
  int*  base       = (int*)carve((size_t)(2 * NN + 1) * 4);
  int*  hist       = (int*)carve((size_t)2 * NN * 4);
  int*  dhist      = (int*)carve(64 * 4);                   // contiguous after hist
  int*  sums       = (int*)carve(256 * 4);
  int*  perm       = rank_dst;   // alias: rank_dst dead after scatter

  hipMemsetAsync(hist, 0, ((size_t)2 * NN + 64) * 4, stream);  // hist + dhist

  const int EB  = (NE + 255) / 256;             // 3125
  const int NB  = (NN + 255) / 256;             // 391
  const int L2N = 2 * NN;                       // 200000
  const int SB1 = (L2N + 1023) / 1024;          // 196
  const int SB3 = (L2N + 255) / 256;            // 782
  const int GB8 = (L2N * 8) / 256;              // 6250 (exact)

  hist_kernel<<<EB, 256, 0, stream>>>(ei, hist, rank_dst, rank_src, out_loss);
  scan1_kernel<<<SB1, 256, 0, stream>>>(hist, base, sums, L2N, dhist);
  scan2_kernel<<<1, 256, 0, stream>>>(sums, SB1, base + L2N, dhist);
  scan3_kernel<<<SB3, 256, 0, stream>>>(base, sums, L2N);
  scatter_kernel<<<EB, 256, 0, stream>>>(ei, ea, a_ij, base, rank_dst, rank_src,
                                         pay, pay_au);
  dperm_kernel<<<SB3, 256, 0, stream>>>(base, dhist, perm);

  const float gw[3] = {0.81f, 0.9f, 1.0f};  // gamma^(K-1-t)

  // t = 0 (h == 0)
  gather_kernel<true, false><<<GB8, 256, 0, stream>>>(
      h, hb16, pay, base, perm,
      phi_to_w1, phi_to_b1, phi_to_w2, phi_to_b2,
      phi_fr_w1, phi_fr_b1, phi_fr_w2, phi_fr_b2,
      mto, mfr, GB8, pay_au, out_u, y, 0.0f, out_loss);
  node_kernel<true><<<NB, 256, 0, stream>>>(
      h, hb16, mto, mfr, prb,
      psi_w1, psi_b1, psi_w2, psi_b2,
      dec_w1, dec_b1, dec_w2, dec_b2, out_u);

  // t = 1, 2: gather(t) fused with au_loss(t-1)
  for (int t = 1; t < 3; ++t) {
    gather_kernel<false, true><<<GB8 + NB, 256, 0, stream>>>(
        h, hb16, pay, base, perm,
        phi_to_w1 + t * 560, phi_to_b1 + t * 16, phi_to_w2 + t * 256, phi_to_b2 + t * 16,
        phi_fr_w1 + t * 560, phi_fr_b1 + t * 16, phi_fr_w2 + t * 256, phi_fr_b2 + t * 16,
        mto, mfr, GB8, pay_au, out_u, y, gw[t - 1] / (float)NN, out_loss);
    node_kernel<false><<<NB, 256, 0, stream>>>(
        h, hb16, mto, mfr, prb,
        psi_w1 + t * 784, psi_b1 + t * 16, psi_w2 + t * 256, psi_b2 + t * 16,
        dec_w1 + t * 256, dec_b1 + t * 16, dec_w2 + t * 16, dec_b2 + t, out_u);
  }

  // final residual loss (t = 2's u)
  gather_kernel<false, true><<<NB, 256, 0, stream>>>(
      h, hb16, pay, base, perm,
      phi_to_w1, phi_to_b1, phi_to_w2, phi_to_b2,
      phi_fr_w1, phi_fr_b1, phi_fr_w2, phi_fr_b2,
      mto, mfr, 0, pay_au, out_u, y, gw[2] / (float)NN, out_loss);
}

// Round 15
// 303.681 us; speedup vs baseline: 1.1519x; 1.0348x over previous
//
#include <hip/hip_runtime.h>

#define NN 100000
#define NE 800000
#define DD 16
#define ALPHA 0.1f

typedef _Float16 h2_t __attribute__((ext_vector_type(2)));
union U32H2 { unsigned u; h2_t h; };

__device__ __forceinline__ unsigned pack2h(float a, float b) {
  U32H2 v; v.h[0] = (_Float16)a; v.h[1] = (_Float16)b; return v.u;
}

// f32 += f16x2 . f16x2  (mixed-precision dot2); exact-math fallback if absent
__device__ __forceinline__ float dot2(unsigned a, unsigned b, float c) {
  U32H2 ua, ub; ua.u = a; ub.u = b;
#if __has_builtin(__builtin_amdgcn_fdot2)
  return __builtin_amdgcn_fdot2(ua.h, ub.h, c, false);
#else
  return fmaf((float)ua.h[0], (float)ub.h[0],
         fmaf((float)ua.h[1], (float)ub.h[1], c));
#endif
}

__device__ __forceinline__ void load16(const float* __restrict__ p, float* r) {
  float4 v0 = *(const float4*)(p + 0);
  float4 v1 = *(const float4*)(p + 4);
  float4 v2 = *(const float4*)(p + 8);
  float4 v3 = *(const float4*)(p + 12);
  r[0]=v0.x; r[1]=v0.y; r[2]=v0.z; r[3]=v0.w;
  r[4]=v1.x; r[5]=v1.y; r[6]=v1.z; r[7]=v1.w;
  r[8]=v2.x; r[9]=v2.y; r[10]=v2.z; r[11]=v2.w;
  r[12]=v3.x; r[13]=v3.y; r[14]=v3.z; r[15]=v3.w;
}

__device__ __forceinline__ void store16(float* __restrict__ p, const float* r) {
  *(float4*)(p + 0)  = make_float4(r[0], r[1], r[2], r[3]);
  *(float4*)(p + 4)  = make_float4(r[4], r[5], r[6], r[7]);
  *(float4*)(p + 8)  = make_float4(r[8], r[9], r[10], r[11]);
  *(float4*)(p + 12) = make_float4(r[12], r[13], r[14], r[15]);
}

// ---------------------------------------------------------------------------
// hist + rank over unified [in | out] histogram of length 2N
// (also zeroes out_loss — saves one memset dispatch)
// ---------------------------------------------------------------------------
__global__ __launch_bounds__(256) void hist_kernel(
    const int* __restrict__ ei, int* __restrict__ hist,
    int* __restrict__ rank_dst, int* __restrict__ rank_src,
    float* __restrict__ out_loss)
{
  int e = blockIdx.x * 256 + threadIdx.x;
  if (e == 0) *out_loss = 0.0f;
  if (e >= NE) return;
  int s = ei[e];
  int d = ei[NE + e];
  rank_dst[e] = atomicAdd(&hist[d], 1);
  rank_src[e] = atomicAdd(&hist[NN + s], 1);
}

__global__ __launch_bounds__(256) void scan1_kernel(
    const int* __restrict__ in, int* __restrict__ out, int* __restrict__ sums, int L)
{
  __shared__ int sh[256];
  int t = threadIdx.x;
  int i0 = blockIdx.x * 1024 + t * 4;
  int v0 = (i0 + 0 < L) ? in[i0 + 0] : 0;
  int v1 = (i0 + 1 < L) ? in[i0 + 1] : 0;
  int v2 = (i0 + 2 < L) ? in[i0 + 2] : 0;
  int v3 = (i0 + 3 < L) ? in[i0 + 3] : 0;
  int tot = v0 + v1 + v2 + v3;
  sh[t] = tot;
  __syncthreads();
  int val = tot;
  for (int off = 1; off < 256; off <<= 1) {
    int x = (t >= off) ? sh[t - off] : 0;
    __syncthreads();
    val += x; sh[t] = val;
    __syncthreads();
  }
  if (t == 255) sums[blockIdx.x] = val;
  int run = val - tot;
  if (i0 + 0 < L) out[i0 + 0] = run; run += v0;
  if (i0 + 1 < L) out[i0 + 1] = run; run += v1;
  if (i0 + 2 < L) out[i0 + 2] = run; run += v2;
  if (i0 + 3 < L) out[i0 + 3] = run;
}

__global__ __launch_bounds__(256) void scan2_kernel(
    int* __restrict__ sums, int nb, int* __restrict__ out_total)
{
  __shared__ int sh[256];
  int t = threadIdx.x;
  int v = (t < nb) ? sums[t] : 0;
  sh[t] = v;
  __syncthreads();
  int val = v;
  for (int off = 1; off < 256; off <<= 1) {
    int x = (t >= off) ? sh[t - off] : 0;
    __syncthreads();
    val += x; sh[t] = val;
    __syncthreads();
  }
  if (t < nb) sums[t] = val - v;
  if (t == 255) *out_total = val;   // sentinel = 2*NE at base[2N]
}

__global__ __launch_bounds__(256) void scan3_kernel(
    int* __restrict__ out, const int* __restrict__ sums, int L)
{
  int i = blockIdx.x * 256 + threadIdx.x;
  if (i < L) out[i] += sums[i >> 10];
}

// atomic-free payload scatter into unified pay[2*NE] (8B packed entries)
// entry: {w0 = nbr:17 | e2f15:15, w1 = f16x2(e0,e1)}; nbr==0x1FFFF => self-loop
__global__ __launch_bounds__(256) void scatter_kernel(
    const int* __restrict__ ei, const float* __restrict__ ea, const float* __restrict__ a,
    const int* __restrict__ base,
    const int* __restrict__ rank_dst, const int* __restrict__ rank_src,
    uint2* __restrict__ pay, float2* __restrict__ pay_au)
{
  int e = blockIdx.x * 256 + threadIdx.x;
  if (e >= NE) return;
  int s = ei[e];
  int d = ei[NE + e];
  float e0 = ea[3 * (size_t)e], e1 = ea[3 * (size_t)e + 1], e2 = ea[3 * (size_t)e + 2];
  unsigned e01 = pack2h(e0, e1);
  U32H2 te; te.h[0] = (_Float16)e2; te.h[1] = (_Float16)0.0f;
  unsigned e2b = (te.u & 0xFFFFu) >> 1;         // 15-bit f16 (mantissa LSB dropped)
  int sl = (s == d);
  unsigned nb_d = sl ? 0x1FFFFu : (unsigned)s;
  unsigned nb_s = sl ? 0x1FFFFu : (unsigned)d;

  int pd = base[d] + rank_dst[e];
  pay[pd] = make_uint2(nb_d | (e2b << 17), e01);
  int ps = base[NN + s] + rank_src[e];
  pay[ps] = make_uint2(nb_s | (e2b << 17), e01);
  pay_au[ps - NE] = make_float2(__int_as_float(d), a[e]);
}

// ---------------------------------------------------------------------------
// Gather: 8-lane subgroup per (node,dir) group in NATURAL order — sequential
// pay reads, contiguous m-writes; hb reads random (inherent).
// ---------------------------------------------------------------------------
template<bool FIRST, bool WITH_AU>
__global__ __launch_bounds__(256) void gather_kernel(
    const float* __restrict__ h, const unsigned* __restrict__ hb,
    const uint2* __restrict__ pay, const int* __restrict__ base,
    const float* __restrict__ to_w1, const float* __restrict__ to_b1,
    const float* __restrict__ to_w2, const float* __restrict__ to_b2,
    const float* __restrict__ fr_w1, const float* __restrict__ fr_b1,
    const float* __restrict__ fr_w2, const float* __restrict__ fr_b2,
    float* __restrict__ mto, float* __restrict__ mfr, int gblocks,
    const float2* __restrict__ pay_au, const float* __restrict__ u,
    const float* __restrict__ y, float w, float* __restrict__ loss)
{
  if (WITH_AU && (int)blockIdx.x >= gblocks) {
    // ---- au_loss body ----
    __shared__ float ss[4];
    int n = (blockIdx.x - gblocks) * 256 + threadIdx.x;
    float acc = 0.0f;
    if (n < NN) {
      float auv = 0.0f;
      int beg = base[NN + n] - NE, end = base[NN + n + 1] - NE;
      for (int i = beg; i < end; ++i) {
        float2 q = pay_au[i];
        auv = fmaf(q.y, u[__float_as_int(q.x)], auv);
      }
      float dlt = auv - y[n];
      acc = dlt * dlt;
    }
    #pragma unroll
    for (int off = 32; off > 0; off >>= 1) acc += __shfl_down(acc, off);
    int lane = threadIdx.x & 63, wid = threadIdx.x >> 6;
    if (lane == 0) ss[wid] = acc;
    __syncthreads();
    if (threadIdx.x == 0) atomicAdd(loss, (ss[0] + ss[1] + ss[2] + ss[3]) * w);
    return;
  }

  // ---- gather body ----
  __shared__ __align__(16) float sw[1696];       // per half (848): w1[560] b1@560 w2@576 b2@832
  __shared__ __align__(16) unsigned w1h[2][144]; // f16 pairs: kp<8 rows {16+2kp,17+2kp}; kp=8 rows {32,33}
  __shared__ __align__(16) float p1buf[512];
  int t = threadIdx.x;
  for (int i = t; i < 560; i += 256) { sw[i] = to_w1[i]; sw[848 + i] = fr_w1[i]; }
  { int i = t;
    if (i < 256) { sw[576 + i] = to_w2[i]; sw[848 + 576 + i] = fr_w2[i]; }
    if (i < 16) {
      sw[560 + i] = to_b1[i];
      sw[832 + i] = to_b2[i];
      sw[848 + 560 + i] = fr_b1[i];
      sw[848 + 832 + i] = fr_b2[i];
    }
  }
  for (int i = t; i < 288; i += 256) {
    int dr = i / 144, idx = i % 144;
    int kp = idx >> 4, j = idx & 15;
    int r0 = (kp < 8) ? (16 + 2 * kp) : 32;
    const float* W = dr ? fr_w1 : to_w1;
    w1h[dr][idx] = pack2h(W[r0 * DD + j], W[(r0 + 1) * DD + j]);
  }
  __syncthreads();

  int g = (blockIdx.x * 256 + t) >> 3;     // natural group order (exact: 2N*8 threads)
  int l = t & 7;
  int dir = (g >= NN) ? 1 : 0;             // 0 = mess_to, 1 = mess_from
  int n = g - (dir ? NN : 0);

  const float* w1 = sw + (dir ? 848 : 0);
  const float* b1 = w1 + 560;
  const float* w2 = w1 + 576;
  const float* b2 = w1 + 832;
  const uint4*  whn4 = (const uint4*)(w1h[dir]);        // nbr pairs, [kp*4+m]
  const uint4*  wha4 = (const uint4*)(w1h[dir] + 128);  // attr rows 32,33
  const float4* wa34 = (const float4*)(w1 + 34 * DD);   // attr row 34 (f32)

  float p1v[DD];
  if (FIRST) {
    #pragma unroll
    for (int j = 0; j < DD; ++j) p1v[j] = b1[j];
  } else {
    // cooperative p1: lane l computes outputs 2l,2l+1 (32 FMA), exchange via LDS
    float hv[DD];
    load16(h + (size_t)n * DD, hv);
    int j0 = 2 * l;
    const float2* b1p = (const float2*)b1;
    float2 pp = b1p[l];
    #pragma unroll
    for (int k = 0; k < DD; ++k) {
      float2 wk = *(const float2*)(w1 + k * DD + j0);
      pp.x = fmaf(hv[k], wk.x, pp.x);
      pp.y = fmaf(hv[k], wk.y, pp.y);
    }
    *(float2*)(p1buf + 2 * t) = pp;
    __syncthreads();
    const float4* pbase = (const float4*)&p1buf[(t & ~7) * 2];
    #pragma unroll
    for (int m = 0; m < 4; ++m) {
      float4 pv = pbase[m];
      p1v[4 * m + 0] = pv.x; p1v[4 * m + 1] = pv.y;
      p1v[4 * m + 2] = pv.z; p1v[4 * m + 3] = pv.w;
    }
  }

  float hs_[DD];
  #pragma unroll
  for (int j = 0; j < DD; ++j) hs_[j] = 0.0f;
  int cntv = 0;

  int beg = base[g], end = base[g + 1];
  for (int i = beg + l; i < end; i += 8) {
    uint2 q = pay[i];
    unsigned nb = q.x & 0x1FFFFu;
    if (nb != 0x1FFFFu) {
      unsigned e01 = q.y;
      U32H2 te; te.u = ((q.x >> 17) << 1) & 0xFFFFu;
      float e2f = (float)te.h[0];
      float hid[DD];
      #pragma unroll
      for (int m = 0; m < 4; ++m) {
        uint4  wq = wha4[m];
        float4 wa = wa34[m];
        hid[4 * m + 0] = fmaf(e2f, wa.x, dot2(e01, wq.x, p1v[4 * m + 0]));
        hid[4 * m + 1] = fmaf(e2f, wa.y, dot2(e01, wq.y, p1v[4 * m + 1]));
        hid[4 * m + 2] = fmaf(e2f, wa.z, dot2(e01, wq.z, p1v[4 * m + 2]));
        hid[4 * m + 3] = fmaf(e2f, wa.w, dot2(e01, wq.w, p1v[4 * m + 3]));
      }
      if (!FIRST) {
        uint4 qa = *(const uint4*)(hb + (size_t)nb * 8);
        uint4 qb = *(const uint4*)(hb + (size_t)nb * 8 + 4);
        unsigned hp[8] = {qa.x, qa.y, qa.z, qa.w, qb.x, qb.y, qb.z, qb.w};
        #pragma unroll
        for (int kp = 0; kp < 8; ++kp) {
          unsigned hv2 = hp[kp];
          #pragma unroll
          for (int m = 0; m < 4; ++m) {
            uint4 wq = whn4[kp * 4 + m];
            hid[4 * m + 0] = dot2(hv2, wq.x, hid[4 * m + 0]);
            hid[4 * m + 1] = dot2(hv2, wq.y, hid[4 * m + 1]);
            hid[4 * m + 2] = dot2(hv2, wq.z, hid[4 * m + 2]);
            hid[4 * m + 3] = dot2(hv2, wq.w, hid[4 * m + 3]);
          }
        }
      }
      #pragma unroll
      for (int j = 0; j < DD; ++j) hs_[j] += fmaxf(hid[j], 0.0f);
      ++cntv;
    }
  }

  // reduce across the 8-lane subgroup
  #pragma unroll
  for (int j = 0; j < DD; ++j) {
    hs_[j] += __shfl_xor(hs_[j], 1, 64);
    hs_[j] += __shfl_xor(hs_[j], 2, 64);
    hs_[j] += __shfl_xor(hs_[j], 4, 64);
  }
  cntv += __shfl_xor(cntv, 1, 64);
  cntv += __shfl_xor(cntv, 2, 64);
  cntv += __shfl_xor(cntv, 4, 64);

  // layer 2 once per group, feature-split: lane l emits outputs [2l, 2l+2)
  float c = (float)cntv;
  const float2* b2p = (const float2*)b2;
  float2 bb = b2p[l];
  float m0 = c * bb.x;
  float m1 = c * bb.y;
  #pragma unroll
  for (int k = 0; k < DD; ++k) {
    float2 wk = *(const float2*)(w2 + k * DD + 2 * l);
    float x = hs_[k];
    m0 = fmaf(x, wk.x, m0);
    m1 = fmaf(x, wk.y, m1);
  }
  float* dst = (dir ? mfr : mto) + (size_t)n * DD + 2 * l;
  *(float2*)dst = make_float2(m0, m1);
}

// ---------------------------------------------------------------------------
// Node kernel: h += ALPHA*psi([h,mto,mfr,prb]); u = dec(h); hb = f16(h)
// FIRST=true: h == 0 -> skip h load and its 16 rows.
// ---------------------------------------------------------------------------
template<bool FIRST>
__global__ __launch_bounds__(256) void node_kernel(
    float* __restrict__ h, unsigned* __restrict__ hb,
    const float* __restrict__ mto, const float* __restrict__ mfr,
    const float* __restrict__ prb,
    const float* __restrict__ psi_w1, const float* __restrict__ psi_b1,
    const float* __restrict__ psi_w2, const float* __restrict__ psi_b2,
    const float* __restrict__ dec_w1, const float* __restrict__ dec_b1,
    const float* __restrict__ dec_w2, const float* __restrict__ dec_b2,
    float* __restrict__ u)
{
  __shared__ __align__(16) float sw[1364];
  for (int i = threadIdx.x; i < 784; i += 256) sw[i] = psi_w1[i];
  { int i = threadIdx.x;
    if (i < 256) { sw[800 + i] = psi_w2[i]; sw[1072 + i] = dec_w1[i]; }
    if (i < 16) {
      sw[784 + i] = psi_b1[i];
      sw[1056 + i] = psi_b2[i];
      sw[1328 + i] = dec_b1[i];
      sw[1344 + i] = dec_w2[i];
    }
    if (i == 0) sw[1360] = dec_b2[0];
  }
  __syncthreads();

  int n = blockIdx.x * 256 + threadIdx.x;
  if (n >= NN) return;

  float hv[DD], mt[DD], mf[DD];
  if (!FIRST) {
    load16(h + (size_t)n * DD, hv);
  } else {
    for (int j = 0; j < DD; ++j) hv[j] = 0.0f;
  }
  load16(mto + (size_t)n * DD, mt);
  load16(mfr + (size_t)n * DD, mf);
  float p = prb[n];

  float hid[DD];
  #pragma unroll
  for (int j = 0; j < DD; ++j) hid[j] = sw[784 + j];
  if (!FIRST) {
    #pragma unroll
    for (int i = 0; i < DD; ++i) {
      float x = hv[i];
      #pragma unroll
      for (int j = 0; j < DD; ++j) hid[j] = fmaf(x, sw[i * DD + j], hid[j]);
    }
  }
  #pragma unroll
  for (int i = 0; i < DD; ++i) {
    float x = mt[i];
    #pragma unroll
    for (int j = 0; j < DD; ++j) hid[j] = fmaf(x, sw[(DD + i) * DD + j], hid[j]);
  }
  #pragma unroll
  for (int i = 0; i < DD; ++i) {
    float x = mf[i];
    #pragma unroll
    for (int j = 0; j < DD; ++j) hid[j] = fmaf(x, sw[(2 * DD + i) * DD + j], hid[j]);
  }
  #pragma unroll
  for (int j = 0; j < DD; ++j) hid[j] = fmaf(p, sw[48 * DD + j], hid[j]);
  #pragma unroll
  for (int j = 0; j < DD; ++j) hid[j] = fmaxf(hid[j], 0.0f);

  float hnew[DD];
  #pragma unroll
  for (int j = 0; j < DD; ++j) hnew[j] = sw[1056 + j];
  #pragma unroll
  for (int i = 0; i < DD; ++i) {
    float x = hid[i];
    #pragma unroll
    for (int j = 0; j < DD; ++j) hnew[j] = fmaf(x, sw[800 + i * DD + j], hnew[j]);
  }
  #pragma unroll
  for (int j = 0; j < DD; ++j) hnew[j] = fmaf(ALPHA, hnew[j], hv[j]);
  store16(h + (size_t)n * DD, hnew);

  uint4 pa, pb;
  pa.x = pack2h(hnew[0],  hnew[1]);
  pa.y = pack2h(hnew[2],  hnew[3]);
  pa.z = pack2h(hnew[4],  hnew[5]);
  pa.w = pack2h(hnew[6],  hnew[7]);
  pb.x = pack2h(hnew[8],  hnew[9]);
  pb.y = pack2h(hnew[10], hnew[11]);
  pb.z = pack2h(hnew[12], hnew[13]);
  pb.w = pack2h(hnew[14], hnew[15]);
  *(uint4*)(hb + (size_t)n * 8)     = pa;
  *(uint4*)(hb + (size_t)n * 8 + 4) = pb;

  float hid2[DD];
  #pragma unroll
  for (int j = 0; j < DD; ++j) hid2[j] = sw[1328 + j];
  #pragma unroll
  for (int i = 0; i < DD; ++i) {
    float x = hnew[i];
    #pragma unroll
    for (int j = 0; j < DD; ++j) hid2[j] = fmaf(x, sw[1072 + i * DD + j], hid2[j]);
  }
  float uo = sw[1360];
  #pragma unroll
  for (int i = 0; i < DD; ++i) uo += fmaxf(hid2[i], 0.0f) * sw[1344 + i];
  u[n] = uo;
}

extern "C" void kernel_launch(void* const* d_in, const int* in_sizes, int n_in,
                              void* d_out, int out_size, void* d_ws, size_t ws_size,
                              hipStream_t stream) {
  const int*   ei        = (const int*)d_in[0];
  const float* ea        = (const float*)d_in[1];
  const float* a_ij      = (const float*)d_in[2];
  const float* prb       = (const float*)d_in[3];
  const float* y         = (const float*)d_in[5];
  const float* phi_to_w1 = (const float*)d_in[6];
  const float* phi_to_b1 = (const float*)d_in[7];
  const float* phi_to_w2 = (const float*)d_in[8];
  const float* phi_to_b2 = (const float*)d_in[9];
  const float* phi_fr_w1 = (const float*)d_in[10];
  const float* phi_fr_b1 = (const float*)d_in[11];
  const float* phi_fr_w2 = (const float*)d_in[12];
  const float* phi_fr_b2 = (const float*)d_in[13];
  const float* psi_w1    = (const float*)d_in[14];
  const float* psi_b1    = (const float*)d_in[15];
  const float* psi_w2    = (const float*)d_in[16];
  const float* psi_b2    = (const float*)d_in[17];
  const float* dec_w1    = (const float*)d_in[18];
  const float* dec_b1    = (const float*)d_in[19];
  const float* dec_w2    = (const float*)d_in[20];
  const float* dec_b2    = (const float*)d_in[21];

  float* out_u    = (float*)d_out;
  float* out_loss = out_u + NN;

  char* wp = (char*)d_ws;
  auto carve = [&](size_t bytes) { void* p = (void*)wp; wp += (bytes + 15) & ~(size_t)15; return p; };
  uint2*    pay    = (uint2*)carve((size_t)2 * NE * 8);     // packed [dst-sorted | src-sorted]
  float2*   pay_au = (float2*)carve((size_t)NE * 8);
  float*    h      = (float*)carve((size_t)NN * DD * 4);
  unsigned* hb16   = (unsigned*)carve((size_t)NN * 8 * 4);  // f16x2 pairs, 8 u32/node
  float*    mto    = (float*)carve((size_t)NN * DD * 4);
  float*    mfr    = (float*)carve((size_t)NN * DD * 4);
  int*  rank_dst   = (int*)carve((size_t)NE * 4);
  int*  rank_src   = (int*)carve((size_t)NE * 4);
  int*  base       = (int*)carve((size_t)(2 * NN + 1) * 4);
  int*  hist       = (int*)carve((size_t)2 * NN * 4);
  int*  sums       = (int*)carve(256 * 4);

  hipMemsetAsync(hist, 0, (size_t)2 * NN * 4, stream);

  const int EB  = (NE + 255) / 256;             // 3125
  const int NB  = (NN + 255) / 256;             // 391
  const int L2N = 2 * NN;                       // 200000
  const int SB1 = (L2N + 1023) / 1024;          // 196
  const int SB3 = (L2N + 255) / 256;            // 782
  const int GB8 = (L2N * 8) / 256;              // 6250 (exact)

  hist_kernel<<<EB, 256, 0, stream>>>(ei, hist, rank_dst, rank_src, out_loss);
  scan1_kernel<<<SB1, 256, 0, stream>>>(hist, base, sums, L2N);
  scan2_kernel<<<1, 256, 0, stream>>>(sums, SB1, base + L2N);
  scan3_kernel<<<SB3, 256, 0, stream>>>(base, sums, L2N);
  scatter_kernel<<<EB, 256, 0, stream>>>(ei, ea, a_ij, base, rank_dst, rank_src,
                                         pay, pay_au);

  const float gw[3] = {0.81f, 0.9f, 1.0f};  // gamma^(K-1-t)

  // t = 0 (h == 0)
  gather_kernel<true, false><<<GB8, 256, 0, stream>>>(
      h, hb16, pay, base,
      phi_to_w1, phi_to_b1, phi_to_w2, phi_to_b2,
      phi_fr_w1, phi_fr_b1, phi_fr_w2, phi_fr_b2,
      mto, mfr, GB8, pay_au, out_u, y, 0.0f, out_loss);
  node_kernel<true><<<NB, 256, 0, stream>>>(
      h, hb16, mto, mfr, prb,
      psi_w1, psi_b1, psi_w2, psi_b2,
      dec_w1, dec_b1, dec_w2, dec_b2, out_u);

  // t = 1, 2: gather(t) fused with au_loss(t-1)
  for (int t = 1; t < 3; ++t) {
    gather_kernel<false, true><<<GB8 + NB, 256, 0, stream>>>(
        h, hb16, pay, base,
        phi_to_w1 + t * 560, phi_to_b1 + t * 16, phi_to_w2 + t * 256, phi_to_b2 + t * 16,
        phi_fr_w1 + t * 560, phi_fr_b1 + t * 16, phi_fr_w2 + t * 256, phi_fr_b2 + t * 16,
        mto, mfr, GB8, pay_au, out_u, y, gw[t - 1] / (float)NN, out_loss);
    node_kernel<false><<<NB, 256, 0, stream>>>(
        h, hb16, mto, mfr, prb,
        psi_w1 + t * 784, psi_b1 + t * 16, psi_w2 + t * 256, psi_b2 + t * 16,
        dec_w1 + t * 256, dec_b1 + t * 16, dec_w2 + t * 16, dec_b2 + t, out_u);
  }

  // final residual loss (t = 2's u)
  gather_kernel<false, true><<<NB, 256, 0, stream>>>(
      h, hb16, pay, base,
      phi_to_w1, phi_to_b1, phi_to_w2, phi_to_b2,
      phi_fr_w1, phi_fr_b1, phi_fr_w2, phi_fr_b2,
      mto, mfr, 0, pay_au, out_u, y, gw[2] / (float)NN, out_loss);
}